// Round 1
// baseline (3847.778 us; speedup 1.0000x reference)
//
#include <hip/hip_runtime.h>
#include <cstdint>

#define BB 4
#define NN 4096
#define EE 16384
#define DD 256
#define ADIM 64
#define TT 16
#define HALFE 8
#define STEPS 3

__device__ __forceinline__ float sigmoidf_(float x) { return 1.0f / (1.0f + __expf(-x)); }

// ---------------- init: ann + h ----------------
__global__ void init_kernel(const int* __restrict__ ann_id,
                            const float* __restrict__ type_embed,
                            float* __restrict__ ann, float* __restrict__ h) {
    int idx = blockIdx.x * 256 + threadIdx.x;           // over B*N*D
    int bn = idx / DD, i = idx % DD;
    int id = ann_id[bn];
    float v = 0.f;
    if (i < ADIM) {
        if (id > 0) v = type_embed[(id - 1) * ADIM + i];
        ann[bn * ADIM + i] = v;
    }
    h[idx] = (i < ADIM) ? v : 0.f;
}

// ---------------- weight repacks (once per call) ----------------
// W2[j][t*D+i] = edge_embed[t][i*D + j]   (K-major for P-GEMM)
__global__ void build_w2(const float* __restrict__ edge_embed, float* __restrict__ W2) {
    int idx = blockIdx.x * 256 + threadIdx.x;           // D*T*D
    int j = idx / (TT * DD);
    int c = idx % (TT * DD);
    int t = c / DD, i = c % DD;
    W2[idx] = edge_embed[t * DD * DD + i * DD + j];
}

// Wcat[k][c]: c<256 -> Wr[c][k]; c<512 -> Wz[c-256][k]; else Wh[c-512][k] (k<512) or 0
__global__ void build_wcat(const float* __restrict__ Wr, const float* __restrict__ Wz,
                           const float* __restrict__ Wh, float* __restrict__ Wcat) {
    int idx = blockIdx.x * 256 + threadIdx.x;           // 768*768
    int k = idx / 768, c = idx % 768;
    float v;
    if (c < 256)       v = Wr[c * 768 + k];
    else if (c < 512)  v = Wz[(c - 256) * 768 + k];
    else               v = (k < 512) ? Wh[(c - 512) * 768 + k] : 0.f;
    Wcat[idx] = v;
}

// Whh[k][i] = Wh[i][512+k]
__global__ void build_whh(const float* __restrict__ Wh, float* __restrict__ Whh) {
    int idx = blockIdx.x * 256 + threadIdx.x;           // 256*256
    int k = idx / 256, i = idx % 256;
    Whh[idx] = Wh[i * 768 + 512 + k];
}

// ---------------- generic fp32 tiled GEMM: C[M,N] = A[M,K] @ B[K,N], row-major ----------------
__global__ __launch_bounds__(256) void gemm_tile(const float* __restrict__ A,
                                                 const float* __restrict__ Bm,
                                                 float* __restrict__ C,
                                                 int M, int N, int K) {
    __shared__ float As[16][65];
    __shared__ float Bs[16][65];
    int tid = threadIdx.x;
    int nb = N / 64;
    int bx = blockIdx.x % nb;
    int by = blockIdx.x / nb;
    int r0 = by * 64, c0 = bx * 64;
    int ty = tid / 16, tx = tid % 16;
    float acc[4][4] = {};
    int ar = tid / 16, ac = tid % 16;     // A tile load coords
    int brr = tid / 64, bcc = tid % 64;   // B tile load coords
    for (int k0 = 0; k0 < K; k0 += 16) {
#pragma unroll
        for (int i = 0; i < 4; i++)
            As[ac][ar + i * 16] = A[(size_t)(r0 + ar + i * 16) * K + k0 + ac];
#pragma unroll
        for (int i = 0; i < 4; i++)
            Bs[brr + i * 4][bcc] = Bm[(size_t)(k0 + brr + i * 4) * N + c0 + bcc];
        __syncthreads();
#pragma unroll
        for (int kk = 0; kk < 16; kk++) {
            float a[4], bv[4];
#pragma unroll
            for (int i = 0; i < 4; i++) a[i] = As[kk][ty * 4 + i];
#pragma unroll
            for (int j = 0; j < 4; j++) bv[j] = Bs[kk][tx * 4 + j];
#pragma unroll
            for (int i = 0; i < 4; i++)
#pragma unroll
                for (int j = 0; j < 4; j++) acc[i][j] += a[i] * bv[j];
        }
        __syncthreads();
    }
#pragma unroll
    for (int i = 0; i < 4; i++) {
        size_t row = r0 + ty * 4 + i;
#pragma unroll
        for (int j = 0; j < 4; j++) C[row * N + c0 + tx * 4 + j] = acc[i][j];
    }
}

// ---------------- per-edge scatter into X = [a_in | a_out | h] ----------------
__global__ void scatter_kernel(const float* __restrict__ P,
                               const int* __restrict__ src, const int* __restrict__ dst,
                               const int* __restrict__ et, const float* __restrict__ bias,
                               float* __restrict__ X) {
    int e = blockIdx.x;
    int i = threadIdx.x;
    int s = src[e], d = dst[e], t = et[e];
    float mo = P[(size_t)d * (TT * DD) + t * DD + i] + bias[t * DD + i];
    atomicAdd(&X[(size_t)s * 768 + 256 + i], mo);
    float mi = P[(size_t)s * (TT * DD) + (t + HALFE) * DD + i] + bias[(t + HALFE) * DD + i];
    atomicAdd(&X[(size_t)d * 768 + i], mi);
}

// X[bn][512+i] = h[bn][i]
__global__ void fill_h(const float* __restrict__ h, float* __restrict__ X) {
    int idx = blockIdx.x * 256 + threadIdx.x;           // B*N*D
    int bn = idx / DD, i = idx % DD;
    X[(size_t)bn * 768 + 512 + i] = h[idx];
}

// r = sig(RZU[:,0:256]+br); RH = r*h; z = sig(RZU[:,256:512]+bz) stored in place
__global__ void elem_rz(float* __restrict__ RZU, const float* __restrict__ br,
                        const float* __restrict__ bz, const float* __restrict__ h,
                        float* __restrict__ RH) {
    int idx = blockIdx.x * 256 + threadIdx.x;           // B*N*D
    int bn = idx / DD, i = idx % DD;
    size_t base = (size_t)bn * 768;
    float r = sigmoidf_(RZU[base + i] + br[i]);
    RH[idx] = r * h[idx];
    float z = sigmoidf_(RZU[base + 256 + i] + bz[i]);
    RZU[base + 256 + i] = z;
}

// h = (1-z)*h + z*tanh(u + hh + bh)
__global__ void update_h(float* __restrict__ h, const float* __restrict__ RZU,
                         const float* __restrict__ HH, const float* __restrict__ bh) {
    int idx = blockIdx.x * 256 + threadIdx.x;           // B*N*D
    int bn = idx / DD, i = idx % DD;
    size_t base = (size_t)bn * 768;
    float z = RZU[base + 256 + i];
    float hhat = tanhf(RZU[base + 512 + i] + HH[idx] + bh[i]);
    float hv = h[idx];
    h[idx] = (1.f - z) * hv + z * hhat;
}

// per-node attention readout, atomicAdd into acc[b]
__global__ void final_reduce(const float* __restrict__ h, const float* __restrict__ ann,
                             const float* __restrict__ Wa, const float* __restrict__ ba,
                             const float* __restrict__ Wo, const float* __restrict__ bo,
                             float* __restrict__ acc) {
    int wave = threadIdx.x >> 6;
    int lane = threadIdx.x & 63;
    int bn = blockIdx.x * 4 + wave;                     // B*N/4 blocks
    float sa = 0.f, so = 0.f;
#pragma unroll
    for (int q = 0; q < 5; q++) {
        int k = lane + q * 64;
        float jv = (k < 256) ? h[(size_t)bn * DD + k] : ann[(size_t)bn * ADIM + (k - 256)];
        sa += jv * Wa[k];
        so += jv * Wo[k];
    }
    for (int off = 32; off; off >>= 1) {
        sa += __shfl_down(sa, off);
        so += __shfl_down(so, off);
    }
    if (lane == 0) {
        float atten = sigmoidf_(sa + ba[0]);
        float ou = tanhf(so + bo[0]);
        atomicAdd(&acc[bn / NN], atten * ou);
    }
}

__global__ void final_out(const float* __restrict__ acc, float* __restrict__ out) {
    int b = threadIdx.x;
    if (b < BB) out[b] = sigmoidf_(acc[b]);
}

extern "C" void kernel_launch(void* const* d_in, const int* in_sizes, int n_in,
                              void* d_out, int out_size, void* d_ws, size_t ws_size,
                              hipStream_t stream) {
    const int*   ann_id     = (const int*)d_in[0];
    const int*   src        = (const int*)d_in[1];
    const int*   dst        = (const int*)d_in[2];
    const int*   etype      = (const int*)d_in[3];
    const float* edge_embed = (const float*)d_in[4];
    const float* edge_bias  = (const float*)d_in[5];
    const float* type_embed = (const float*)d_in[6];
    const float* Wr = (const float*)d_in[7];
    const float* br = (const float*)d_in[8];
    const float* Wz = (const float*)d_in[9];
    const float* bz = (const float*)d_in[10];
    const float* Wh = (const float*)d_in[11];
    const float* bh = (const float*)d_in[12];
    const float* Wa = (const float*)d_in[13];
    const float* ba = (const float*)d_in[14];
    const float* Wo = (const float*)d_in[15];
    const float* bo = (const float*)d_in[16];
    float* out = (float*)d_out;

    float* ws = (float*)d_ws;
    size_t off = 0;
    float* ann  = ws + off; off += (size_t)BB * NN * ADIM;   // 1,048,576
    float* h    = ws + off; off += (size_t)BB * NN * DD;     // 4,194,304
    float* W2   = ws + off; off += (size_t)DD * TT * DD;     // 1,048,576
    float* Wcat = ws + off; off += 768 * 768;                // 589,824
    float* Whh  = ws + off; off += 256 * 256;                // 65,536
    float* P    = ws + off; off += (size_t)NN * TT * DD;     // 16,777,216 (per-b reuse)
    float* X    = ws + off; off += (size_t)BB * NN * 768;    // 12,582,912
    float* RZU  = ws + off; off += (size_t)BB * NN * 768;    // 12,582,912
    float* RH   = ws + off; off += (size_t)BB * NN * DD;     // 4,194,304
    float* HH   = ws + off; off += (size_t)BB * NN * DD;     // 4,194,304
    float* acc  = ws + off; off += 16;
    // total ~219 MB of d_ws

    // ---- prep ----
    hipLaunchKernelGGL(init_kernel, dim3((BB * NN * DD) / 256), dim3(256), 0, stream,
                       ann_id, type_embed, ann, h);
    hipLaunchKernelGGL(build_w2, dim3((DD * TT * DD) / 256), dim3(256), 0, stream,
                       edge_embed, W2);
    hipLaunchKernelGGL(build_wcat, dim3((768 * 768) / 256), dim3(256), 0, stream,
                       Wr, Wz, Wh, Wcat);
    hipLaunchKernelGGL(build_whh, dim3((256 * 256) / 256), dim3(256), 0, stream,
                       Wh, Whh);

    for (int s = 0; s < STEPS; ++s) {
        hipMemsetAsync(X, 0, (size_t)BB * NN * 768 * sizeof(float), stream);
        hipLaunchKernelGGL(fill_h, dim3((BB * NN * DD) / 256), dim3(256), 0, stream, h, X);
        for (int b = 0; b < BB; ++b) {
            // P = h_b [N,D] @ W2 [D, T*D]
            hipLaunchKernelGGL(gemm_tile, dim3((NN / 64) * ((TT * DD) / 64)), dim3(256), 0,
                               stream, h + (size_t)b * NN * DD, W2, P, NN, TT * DD, DD);
            hipLaunchKernelGGL(scatter_kernel, dim3(EE), dim3(256), 0, stream,
                               P, src + b * EE, dst + b * EE, etype + b * EE, edge_bias,
                               X + (size_t)b * NN * 768);
        }
        // RZU = X [B*N,768] @ Wcat [768,768]
        hipLaunchKernelGGL(gemm_tile, dim3(((BB * NN) / 64) * (768 / 64)), dim3(256), 0,
                           stream, X, Wcat, RZU, BB * NN, 768, 768);
        hipLaunchKernelGGL(elem_rz, dim3((BB * NN * DD) / 256), dim3(256), 0, stream,
                           RZU, br, bz, h, RH);
        // HH = RH [B*N,256] @ Whh [256,256]
        hipLaunchKernelGGL(gemm_tile, dim3(((BB * NN) / 64) * (256 / 64)), dim3(256), 0,
                           stream, RH, Whh, HH, BB * NN, 256, 256);
        hipLaunchKernelGGL(update_h, dim3((BB * NN * DD) / 256), dim3(256), 0, stream,
                           h, RZU, HH, bh);
    }

    hipMemsetAsync(acc, 0, 16 * sizeof(float), stream);
    hipLaunchKernelGGL(final_reduce, dim3((BB * NN) / 4), dim3(256), 0, stream,
                       h, ann, Wa, ba, Wo, bo, acc);
    hipLaunchKernelGGL(final_out, dim3(1), dim3(64), 0, stream, acc, out);
}

// Round 2
// 1144.802 us; speedup vs baseline: 3.3611x; 3.3611x over previous
//
#include <hip/hip_runtime.h>
#include <cstdint>

#define BB 4
#define NN 4096
#define EE 16384
#define DD 256
#define ADIM 64
#define TT 16
#define HALFE 8
#define STEPS 3

typedef __attribute__((ext_vector_type(8))) short short8;
typedef __attribute__((ext_vector_type(4))) float f32x4;

__device__ __forceinline__ float sigmoidf_(float x) { return 1.0f / (1.0f + __expf(-x)); }

__device__ __forceinline__ unsigned short f2bf(float x) {
    unsigned u = __float_as_uint(x);
    u += 0x7fffu + ((u >> 16) & 1u);
    return (unsigned short)(u >> 16);
}
__device__ __forceinline__ float bf2f(unsigned short b) {
    return __uint_as_float(((unsigned)b) << 16);
}

// ---------------- init: ann + h ----------------
__global__ void init_kernel(const int* __restrict__ ann_id,
                            const float* __restrict__ type_embed,
                            float* __restrict__ ann, float* __restrict__ h) {
    int idx = blockIdx.x * 256 + threadIdx.x;           // over B*N*D
    int bn = idx / DD, i = idx % DD;
    int id = ann_id[bn];
    float v = 0.f;
    if (i < ADIM) {
        if (id > 0) v = type_embed[(id - 1) * ADIM + i];
        ann[bn * ADIM + i] = v;
    }
    h[idx] = (i < ADIM) ? v : 0.f;
}

// ---------------- fp32 -> bf16 conversion, 4 elems/thread ----------------
__global__ void conv_f2b4(const float* __restrict__ in, unsigned short* __restrict__ out) {
    int idx = blockIdx.x * 256 + threadIdx.x;
    float4 v = ((const float4*)in)[idx];
    ushort4 o;
    o.x = f2bf(v.x); o.y = f2bf(v.y); o.z = f2bf(v.z); o.w = f2bf(v.w);
    ((ushort4*)out)[idx] = o;
}

// Wcat_t[c][k] (B^T layout): c<256 -> Wr[c][k]; c<512 -> Wz[c-256][k]; else Wh[c-512][k] (k<512) or 0
__global__ void build_wcat(const float* __restrict__ Wr, const float* __restrict__ Wz,
                           const float* __restrict__ Wh, unsigned short* __restrict__ W) {
    int idx = blockIdx.x * 256 + threadIdx.x;           // 768*768
    int c = idx / 768, k = idx % 768;
    float v;
    if (c < 256)       v = Wr[c * 768 + k];
    else if (c < 512)  v = Wz[(c - 256) * 768 + k];
    else               v = (k < 512) ? Wh[(c - 512) * 768 + k] : 0.f;
    W[idx] = f2bf(v);
}

// Whh_t[i][k] = Wh[i][512+k]
__global__ void build_whh(const float* __restrict__ Wh, unsigned short* __restrict__ W) {
    int idx = blockIdx.x * 256 + threadIdx.x;           // 256*256
    int i = idx / 256, k = idx % 256;
    W[idx] = f2bf(Wh[i * 768 + 512 + k]);
}

// ---------------- bf16 MFMA GEMM: C[M,N] = A[M,K] @ Bt[N,K]^T ----------------
// m97 structure: 128x128 tile, 4 waves (2x2), each wave 64x64 = 4x4 frags of 16x16,
// BK=32, global_load_lds width 16, linear LDS.
template <int BF16OUT>
__global__ __launch_bounds__(256) void gemm_bt(const unsigned short* __restrict__ A,
                                               const unsigned short* __restrict__ Bt,
                                               void* __restrict__ Cv,
                                               int M, int Nn, int K) {
    __shared__ __align__(16) unsigned short As[128 * 32];
    __shared__ __align__(16) unsigned short Bs[128 * 32];
    const int tid = threadIdx.x;
    const int nb = Nn >> 7;
    const int bx = blockIdx.x % nb, by = blockIdx.x / nb;
    const int r0 = by << 7, c0 = bx << 7;
    const int wid = tid >> 6, lane = tid & 63;
    const int wr = wid >> 1, wc = wid & 1;
    const int lr = lane & 15, lk = (lane >> 4) << 3;

    // staging: chunk q = i*256 + tid covers LDS bytes [q*16, q*16+16) = row q/4, cols (q%4)*8..+8
    const unsigned short* Ag = A + (size_t)(r0 + (tid >> 2)) * K + ((tid & 3) << 3);
    const unsigned short* Bg = Bt + (size_t)(c0 + (tid >> 2)) * K + ((tid & 3) << 3);
    char* AsB = (char*)As + wid * 1024;
    char* BsB = (char*)Bs + wid * 1024;

    f32x4 acc[4][4] = {};

    for (int k0 = 0; k0 < K; k0 += 32) {
#pragma unroll
        for (int i = 0; i < 2; ++i) {
            __builtin_amdgcn_global_load_lds(
                (const __attribute__((address_space(1))) void*)(Ag + (size_t)(i * 64) * K + k0),
                (__attribute__((address_space(3))) void*)(AsB + i * 4096), 16, 0, 0);
            __builtin_amdgcn_global_load_lds(
                (const __attribute__((address_space(1))) void*)(Bg + (size_t)(i * 64) * K + k0),
                (__attribute__((address_space(3))) void*)(BsB + i * 4096), 16, 0, 0);
        }
        __syncthreads();
        short8 af[4], bfv[4];
#pragma unroll
        for (int m = 0; m < 4; ++m)
            af[m] = *(const short8*)&As[(wr * 64 + m * 16 + lr) * 32 + lk];
#pragma unroll
        for (int n = 0; n < 4; ++n)
            bfv[n] = *(const short8*)&Bs[(wc * 64 + n * 16 + lr) * 32 + lk];
#pragma unroll
        for (int m = 0; m < 4; ++m)
#pragma unroll
            for (int n = 0; n < 4; ++n)
                acc[m][n] = __builtin_amdgcn_mfma_f32_16x16x32_bf16(af[m], bfv[n], acc[m][n], 0, 0, 0);
        __syncthreads();
    }

    const int crow = r0 + wr * 64 + ((lane >> 4) << 2);
    const int ccol = c0 + wc * 64 + lr;
    if (BF16OUT) {
        unsigned short* C = (unsigned short*)Cv;
#pragma unroll
        for (int m = 0; m < 4; ++m)
#pragma unroll
            for (int n = 0; n < 4; ++n)
#pragma unroll
                for (int j = 0; j < 4; ++j)
                    C[(size_t)(crow + m * 16 + j) * Nn + ccol + n * 16] = f2bf(acc[m][n][j]);
    } else {
        float* C = (float*)Cv;
#pragma unroll
        for (int m = 0; m < 4; ++m)
#pragma unroll
            for (int n = 0; n < 4; ++n)
#pragma unroll
                for (int j = 0; j < 4; ++j)
                    C[(size_t)(crow + m * 16 + j) * Nn + ccol + n * 16] = acc[m][n][j];
    }
}

// ---------------- X init: [a_in=0 | a_out=0 | h] ----------------
__global__ void init_X(const float* __restrict__ h, float* __restrict__ X) {
    int idx = blockIdx.x * 256 + threadIdx.x;           // B*N*768
    int bn = idx / 768, c = idx % 768;
    X[idx] = (c >= 512) ? h[(size_t)bn * DD + (c - 512)] : 0.f;
}

// ---------------- per-edge scatter into X = [a_in | a_out | h], P is bf16 ----------------
__global__ void scatter_kernel(const unsigned short* __restrict__ P,
                               const int* __restrict__ src, const int* __restrict__ dst,
                               const int* __restrict__ et, const float* __restrict__ bias,
                               float* __restrict__ X) {
    int e = blockIdx.x;
    int i = threadIdx.x;
    int s = src[e], d = dst[e], t = et[e];
    float mo = bf2f(P[(size_t)d * (TT * DD) + t * DD + i]) + bias[t * DD + i];
    atomicAdd(&X[(size_t)s * 768 + 256 + i], mo);
    float mi = bf2f(P[(size_t)s * (TT * DD) + (t + HALFE) * DD + i]) + bias[(t + HALFE) * DD + i];
    atomicAdd(&X[(size_t)d * 768 + i], mi);
}

// r = sig(RZU[:,0:256]+br); RH = bf16(r*h); z = sig(RZU[:,256:512]+bz) stored in place
__global__ void elem_rz(float* __restrict__ RZU, const float* __restrict__ br,
                        const float* __restrict__ bz, const float* __restrict__ h,
                        unsigned short* __restrict__ RH) {
    int idx = blockIdx.x * 256 + threadIdx.x;           // B*N*D
    int bn = idx / DD, i = idx % DD;
    size_t base = (size_t)bn * 768;
    float r = sigmoidf_(RZU[base + i] + br[i]);
    RH[idx] = f2bf(r * h[idx]);
    float z = sigmoidf_(RZU[base + 256 + i] + bz[i]);
    RZU[base + 256 + i] = z;
}

// h = (1-z)*h + z*tanh(u + hh + bh)
__global__ void update_h(float* __restrict__ h, const float* __restrict__ RZU,
                         const float* __restrict__ HH, const float* __restrict__ bh) {
    int idx = blockIdx.x * 256 + threadIdx.x;           // B*N*D
    int bn = idx / DD, i = idx % DD;
    size_t base = (size_t)bn * 768;
    float z = RZU[base + 256 + i];
    float hhat = tanhf(RZU[base + 512 + i] + HH[idx] + bh[i]);
    float hv = h[idx];
    h[idx] = (1.f - z) * hv + z * hhat;
}

// per-node attention readout, atomicAdd into acc[b]
__global__ void final_reduce(const float* __restrict__ h, const float* __restrict__ ann,
                             const float* __restrict__ Wa, const float* __restrict__ ba,
                             const float* __restrict__ Wo, const float* __restrict__ bo,
                             float* __restrict__ acc) {
    int wave = threadIdx.x >> 6;
    int lane = threadIdx.x & 63;
    int bn = blockIdx.x * 4 + wave;                     // B*N/4 blocks
    float sa = 0.f, so = 0.f;
#pragma unroll
    for (int q = 0; q < 5; q++) {
        int k = lane + q * 64;
        float jv = (k < 256) ? h[(size_t)bn * DD + k] : ann[(size_t)bn * ADIM + (k - 256)];
        sa += jv * Wa[k];
        so += jv * Wo[k];
    }
    for (int off = 32; off; off >>= 1) {
        sa += __shfl_down(sa, off);
        so += __shfl_down(so, off);
    }
    if (lane == 0) {
        float atten = sigmoidf_(sa + ba[0]);
        float ou = tanhf(so + bo[0]);
        atomicAdd(&acc[bn / NN], atten * ou);
    }
}

__global__ void final_out(const float* __restrict__ acc, float* __restrict__ out) {
    int b = threadIdx.x;
    if (b < BB) out[b] = sigmoidf_(acc[b]);
}

extern "C" void kernel_launch(void* const* d_in, const int* in_sizes, int n_in,
                              void* d_out, int out_size, void* d_ws, size_t ws_size,
                              hipStream_t stream) {
    const int*   ann_id     = (const int*)d_in[0];
    const int*   src        = (const int*)d_in[1];
    const int*   dst        = (const int*)d_in[2];
    const int*   etype      = (const int*)d_in[3];
    const float* edge_embed = (const float*)d_in[4];
    const float* edge_bias  = (const float*)d_in[5];
    const float* type_embed = (const float*)d_in[6];
    const float* Wr = (const float*)d_in[7];
    const float* br = (const float*)d_in[8];
    const float* Wz = (const float*)d_in[9];
    const float* bz = (const float*)d_in[10];
    const float* Wh = (const float*)d_in[11];
    const float* bh = (const float*)d_in[12];
    const float* Wa = (const float*)d_in[13];
    const float* ba = (const float*)d_in[14];
    const float* Wo = (const float*)d_in[15];
    const float* bo = (const float*)d_in[16];
    float* out = (float*)d_out;

    char* base = (char*)d_ws;
    size_t off = 0;
    auto alloc = [&](size_t bytes) { char* p = base + off; off += (bytes + 255) & ~(size_t)255; return p; };
    float* ann  = (float*)alloc((size_t)BB * NN * ADIM * 4);         // 4 MB
    float* h    = (float*)alloc((size_t)BB * NN * DD * 4);           // 16 MB
    float* X    = (float*)alloc((size_t)BB * NN * 768 * 4);          // 48 MB
    float* RZU  = (float*)alloc((size_t)BB * NN * 768 * 4);          // 48 MB
    float* HH   = (float*)alloc((size_t)BB * NN * DD * 4);           // 16 MB
    float* acc  = (float*)alloc(64);
    unsigned short* h_bf   = (unsigned short*)alloc((size_t)BB * NN * DD * 2);   // 8 MB
    unsigned short* W2bf   = (unsigned short*)alloc((size_t)TT * DD * DD * 2);   // 2 MB
    unsigned short* Wcatbf = (unsigned short*)alloc(768 * 768 * 2);
    unsigned short* Whhbf  = (unsigned short*)alloc(256 * 256 * 2);
    unsigned short* P      = (unsigned short*)alloc((size_t)NN * TT * DD * 2);   // 32 MB (per-b reuse)
    unsigned short* Xbf    = (unsigned short*)alloc((size_t)BB * NN * 768 * 2);  // 24 MB
    unsigned short* RHbf   = (unsigned short*)alloc((size_t)BB * NN * DD * 2);   // 8 MB
    // total ~210 MB

    // ---- prep (once per call) ----
    init_kernel<<<dim3((BB * NN * DD) / 256), dim3(256), 0, stream>>>(ann_id, type_embed, ann, h);
    // W2t (B^T layout) == edge_embed flat, just cast to bf16
    conv_f2b4<<<dim3((TT * DD * DD) / 1024), dim3(256), 0, stream>>>(edge_embed, W2bf);
    build_wcat<<<dim3((768 * 768) / 256), dim3(256), 0, stream>>>(Wr, Wz, Wh, Wcatbf);
    build_whh<<<dim3((256 * 256) / 256), dim3(256), 0, stream>>>(Wh, Whhbf);

    for (int s = 0; s < STEPS; ++s) {
        conv_f2b4<<<dim3((BB * NN * DD) / 1024), dim3(256), 0, stream>>>(h, h_bf);
        init_X<<<dim3((BB * NN * 768) / 256), dim3(256), 0, stream>>>(h, X);
        for (int b = 0; b < BB; ++b) {
            // P = h_b [4096,256] @ W2t^T -> [4096, 4096] bf16
            gemm_bt<1><<<dim3((NN / 128) * ((TT * DD) / 128)), dim3(256), 0, stream>>>(
                h_bf + (size_t)b * NN * DD, W2bf, P, NN, TT * DD, DD);
            scatter_kernel<<<dim3(EE), dim3(256), 0, stream>>>(
                P, src + b * EE, dst + b * EE, etype + b * EE, edge_bias,
                X + (size_t)b * NN * 768);
        }
        conv_f2b4<<<dim3((BB * NN * 768) / 1024), dim3(256), 0, stream>>>(X, Xbf);
        // RZU = Xbf [16384,768] @ Wcat_t^T -> fp32
        gemm_bt<0><<<dim3(((BB * NN) / 128) * (768 / 128)), dim3(256), 0, stream>>>(
            Xbf, Wcatbf, RZU, BB * NN, 768, 768);
        elem_rz<<<dim3((BB * NN * DD) / 256), dim3(256), 0, stream>>>(RZU, br, bz, h, RHbf);
        // HH = RHbf [16384,256] @ Whh_t^T -> fp32
        gemm_bt<0><<<dim3(((BB * NN) / 128) * (256 / 128)), dim3(256), 0, stream>>>(
            RHbf, Whhbf, HH, BB * NN, 256, 256);
        update_h<<<dim3((BB * NN * DD) / 256), dim3(256), 0, stream>>>(h, RZU, HH, bh);
    }

    hipMemsetAsync(acc, 0, 64, stream);
    final_reduce<<<dim3((BB * NN) / 4), dim3(256), 0, stream>>>(h, ann, Wa, ba, Wo, bo, acc);
    final_out<<<dim3(1), dim3(64), 0, stream>>>(acc, out);
}

// Round 5
// 725.291 us; speedup vs baseline: 5.3051x; 1.5784x over previous
//
#include <hip/hip_runtime.h>
#include <cstdint>

#define BB 4
#define NN 4096
#define EE 16384
#define DD 256
#define ADIM 64
#define TT 16
#define HALFE 8
#define STEPS 3
#define OSTRIDE 4160

typedef __attribute__((ext_vector_type(8))) short short8;
typedef __attribute__((ext_vector_type(4))) float f32x4;

__device__ __forceinline__ float sigmoidf_(float x) { return 1.0f / (1.0f + __expf(-x)); }

__device__ __forceinline__ unsigned short f2bf(float x) {
    unsigned u = __float_as_uint(x);
    u += 0x7fffu + ((u >> 16) & 1u);
    return (unsigned short)(u >> 16);
}
__device__ __forceinline__ float bf2f(unsigned short b) {
    return __uint_as_float(((unsigned)b) << 16);
}

// ---------------- init: ann, h, h_bf, Xbf[:,512:768] ----------------
__global__ void init_kernel(const int* __restrict__ ann_id,
                            const float* __restrict__ type_embed,
                            float* __restrict__ ann, float* __restrict__ h,
                            unsigned short* __restrict__ hbf,
                            unsigned short* __restrict__ Xbf) {
    int idx = blockIdx.x * 256 + threadIdx.x;   // B*N*64 threads, 4 elems each
    int bn = idx >> 6, q = idx & 63;
    int id = ann_id[bn];
    float4 v = {0.f, 0.f, 0.f, 0.f};
    if (q < 16) {
        if (id > 0) v = ((const float4*)(type_embed + (size_t)(id - 1) * ADIM))[q];
        ((float4*)(ann + (size_t)bn * ADIM))[q] = v;
    }
    ((float4*)(h + (size_t)bn * DD))[q] = v;
    ushort4 o;
    o.x = f2bf(v.x); o.y = f2bf(v.y); o.z = f2bf(v.z); o.w = f2bf(v.w);
    ((ushort4*)(hbf + (size_t)bn * DD))[q] = o;
    ((ushort4*)(Xbf + (size_t)bn * 768 + 512))[q] = o;
}

// ---------------- fp32 -> bf16, 4 elems/thread ----------------
__global__ void conv_f2b4(const float* __restrict__ in, unsigned short* __restrict__ out) {
    int idx = blockIdx.x * 256 + threadIdx.x;
    float4 v = ((const float4*)in)[idx];
    ushort4 o;
    o.x = f2bf(v.x); o.y = f2bf(v.y); o.z = f2bf(v.z); o.w = f2bf(v.w);
    ((ushort4*)out)[idx] = o;
}

// Wcat_t[c][k] (B^T layout)
__global__ void build_wcat(const float* __restrict__ Wr, const float* __restrict__ Wz,
                           const float* __restrict__ Wh, unsigned short* __restrict__ W) {
    int idx = blockIdx.x * 256 + threadIdx.x;   // 768*768
    int c = idx / 768, k = idx % 768;
    float v;
    if (c < 256)       v = Wr[c * 768 + k];
    else if (c < 512)  v = Wz[(c - 256) * 768 + k];
    else               v = (k < 512) ? Wh[(c - 512) * 768 + k] : 0.f;
    W[idx] = f2bf(v);
}

// Whh_t[i][k] = Wh[i][512+k]
__global__ void build_whh(const float* __restrict__ Wh, unsigned short* __restrict__ W) {
    int idx = blockIdx.x * 256 + threadIdx.x;   // 256*256
    int i = idx / 256, k = idx % 256;
    W[idx] = f2bf(Wh[i * 768 + 512 + k]);
}

// ---------------- CSR build ----------------
__global__ void count_kernel(const int* __restrict__ src, const int* __restrict__ dst,
                             int* __restrict__ counts) {
    int idx = blockIdx.x * 256 + threadIdx.x;   // B*E
    int b = idx >> 14;
    atomicAdd(&counts[(b * 2 + 0) * NN + src[idx]], 1);
    atomicAdd(&counts[(b * 2 + 1) * NN + dst[idx]], 1);
}

__global__ __launch_bounds__(1024) void scan_kernel(const int* __restrict__ counts,
                                                    int* __restrict__ offs,
                                                    int* __restrict__ cursor) {
    __shared__ int lsum[1024];
    int t = threadIdx.x, seg = blockIdx.x;      // 8 segments of 4096
    int4 v = ((const int4*)(counts + (size_t)seg * NN))[t];
    int s1 = v.x + v.y, s2 = s1 + v.z, s3 = s2 + v.w;
    lsum[t] = s3;
    __syncthreads();
    for (int off = 1; off < 1024; off <<= 1) {
        int tmp = (t >= off) ? lsum[t - off] : 0;
        __syncthreads();
        lsum[t] += tmp;
        __syncthreads();
    }
    int base = lsum[t] - s3;
    int* o = offs + (size_t)seg * OSTRIDE;
    o[4 * t] = base; o[4 * t + 1] = base + v.x; o[4 * t + 2] = base + s1; o[4 * t + 3] = base + s2;
    if (t == 1023) o[4096] = lsum[1023];
    int* c = cursor + (size_t)seg * NN;
    c[4 * t] = base; c[4 * t + 1] = base + v.x; c[4 * t + 2] = base + s1; c[4 * t + 3] = base + s2;
}

__global__ void fill_kernel(const int* __restrict__ src, const int* __restrict__ dst,
                            const int* __restrict__ et, int* __restrict__ cursor,
                            int* __restrict__ entries) {
    int idx = blockIdx.x * 256 + threadIdx.x;   // B*E
    int b = idx >> 14;
    int s = src[idx], d = dst[idx], t = et[idx];
    int p0 = atomicAdd(&cursor[(b * 2 + 0) * NN + s], 1);
    entries[(size_t)(b * 2 + 0) * EE + p0] = (d << 4) | t;
    int p1 = atomicAdd(&cursor[(b * 2 + 1) * NN + d], 1);
    entries[(size_t)(b * 2 + 1) * EE + p1] = (s << 4) | (t + 8);
}

// ---------------- bf16 MFMA GEMM: C[M,N] = A[M,K] @ Bt[N,K]^T ----------------
template <int BF16OUT>
__global__ __launch_bounds__(256) void gemm_bt(const unsigned short* __restrict__ A,
                                               const unsigned short* __restrict__ Bt,
                                               void* __restrict__ Cv,
                                               int M, int Nn, int K) {
    __shared__ __align__(16) unsigned short As[128 * 32];
    __shared__ __align__(16) unsigned short Bs[128 * 32];
    const int tid = threadIdx.x;
    const int nb = Nn >> 7;
    const int bx = blockIdx.x % nb, by = blockIdx.x / nb;
    const int r0 = by << 7, c0 = bx << 7;
    const int wid = tid >> 6, lane = tid & 63;
    const int wr = wid >> 1, wc = wid & 1;
    const int lr = lane & 15, lk = (lane >> 4) << 3;

    const unsigned short* Ag = A + (size_t)(r0 + (tid >> 2)) * K + ((tid & 3) << 3);
    const unsigned short* Bg = Bt + (size_t)(c0 + (tid >> 2)) * K + ((tid & 3) << 3);
    char* AsB = (char*)As + wid * 1024;
    char* BsB = (char*)Bs + wid * 1024;

    f32x4 acc[4][4] = {};

    for (int k0 = 0; k0 < K; k0 += 32) {
#pragma unroll
        for (int i = 0; i < 2; ++i) {
            __builtin_amdgcn_global_load_lds(
                (const __attribute__((address_space(1))) void*)(Ag + (size_t)(i * 64) * K + k0),
                (__attribute__((address_space(3))) void*)(AsB + i * 4096), 16, 0, 0);
            __builtin_amdgcn_global_load_lds(
                (const __attribute__((address_space(1))) void*)(Bg + (size_t)(i * 64) * K + k0),
                (__attribute__((address_space(3))) void*)(BsB + i * 4096), 16, 0, 0);
        }
        __syncthreads();
        short8 af[4], bfv[4];
#pragma unroll
        for (int m = 0; m < 4; ++m)
            af[m] = *(const short8*)&As[(wr * 64 + m * 16 + lr) * 32 + lk];
#pragma unroll
        for (int n = 0; n < 4; ++n)
            bfv[n] = *(const short8*)&Bs[(wc * 64 + n * 16 + lr) * 32 + lk];
#pragma unroll
        for (int m = 0; m < 4; ++m)
#pragma unroll
            for (int n = 0; n < 4; ++n)
                acc[m][n] = __builtin_amdgcn_mfma_f32_16x16x32_bf16(af[m], bfv[n], acc[m][n], 0, 0, 0);
        __syncthreads();
    }

    const int crow = r0 + wr * 64 + ((lane >> 4) << 2);
    const int ccol = c0 + wc * 64 + lr;
    if (BF16OUT) {
        unsigned short* C = (unsigned short*)Cv;
#pragma unroll
        for (int m = 0; m < 4; ++m)
#pragma unroll
            for (int n = 0; n < 4; ++n)
#pragma unroll
                for (int j = 0; j < 4; ++j)
                    C[(size_t)(crow + m * 16 + j) * Nn + ccol + n * 16] = f2bf(acc[m][n][j]);
    } else {
        float* C = (float*)Cv;
#pragma unroll
        for (int m = 0; m < 4; ++m)
#pragma unroll
            for (int n = 0; n < 4; ++n)
#pragma unroll
                for (int j = 0; j < 4; ++j)
                    C[(size_t)(crow + m * 16 + j) * Nn + ccol + n * 16] = acc[m][n][j];
    }
}

// ---------------- RZU GEMM with fused GRU-gate epilogue ----------------
// C = Xbf[16384,768] @ Wcat_t^T; cols 0:256 -> RH=bf16(sig(v+br)*h), 256:512 -> Z=sig(v+bz), 512:768 -> U=v
__global__ __launch_bounds__(256) void gemm_rzu(const unsigned short* __restrict__ A,
                                                const unsigned short* __restrict__ Bt,
                                                const float* __restrict__ br,
                                                const float* __restrict__ bz,
                                                const float* __restrict__ h,
                                                unsigned short* __restrict__ RH,
                                                float* __restrict__ Z,
                                                float* __restrict__ U) {
    const int K = 768, Nn = 768;
    __shared__ __align__(16) unsigned short As[128 * 32];
    __shared__ __align__(16) unsigned short Bs[128 * 32];
    const int tid = threadIdx.x;
    const int nb = Nn >> 7;
    const int bx = blockIdx.x % nb, by = blockIdx.x / nb;
    const int r0 = by << 7, c0 = bx << 7;
    const int wid = tid >> 6, lane = tid & 63;
    const int wr = wid >> 1, wc = wid & 1;
    const int lr = lane & 15, lk = (lane >> 4) << 3;

    const unsigned short* Ag = A + (size_t)(r0 + (tid >> 2)) * K + ((tid & 3) << 3);
    const unsigned short* Bg = Bt + (size_t)(c0 + (tid >> 2)) * K + ((tid & 3) << 3);
    char* AsB = (char*)As + wid * 1024;
    char* BsB = (char*)Bs + wid * 1024;

    f32x4 acc[4][4] = {};

    for (int k0 = 0; k0 < K; k0 += 32) {
#pragma unroll
        for (int i = 0; i < 2; ++i) {
            __builtin_amdgcn_global_load_lds(
                (const __attribute__((address_space(1))) void*)(Ag + (size_t)(i * 64) * K + k0),
                (__attribute__((address_space(3))) void*)(AsB + i * 4096), 16, 0, 0);
            __builtin_amdgcn_global_load_lds(
                (const __attribute__((address_space(1))) void*)(Bg + (size_t)(i * 64) * K + k0),
                (__attribute__((address_space(3))) void*)(BsB + i * 4096), 16, 0, 0);
        }
        __syncthreads();
        short8 af[4], bfv[4];
#pragma unroll
        for (int m = 0; m < 4; ++m)
            af[m] = *(const short8*)&As[(wr * 64 + m * 16 + lr) * 32 + lk];
#pragma unroll
        for (int n = 0; n < 4; ++n)
            bfv[n] = *(const short8*)&Bs[(wc * 64 + n * 16 + lr) * 32 + lk];
#pragma unroll
        for (int m = 0; m < 4; ++m)
#pragma unroll
            for (int n = 0; n < 4; ++n)
                acc[m][n] = __builtin_amdgcn_mfma_f32_16x16x32_bf16(af[m], bfv[n], acc[m][n], 0, 0, 0);
        __syncthreads();
    }

    const int crow = r0 + wr * 64 + ((lane >> 4) << 2);
    const int ccol = c0 + wc * 64 + lr;
    const int region = c0 >> 8;   // each 128-wide block lies in one 256-aligned region
#pragma unroll
    for (int m = 0; m < 4; ++m)
#pragma unroll
        for (int n = 0; n < 4; ++n)
#pragma unroll
            for (int j = 0; j < 4; ++j) {
                int gr = crow + m * 16 + j;
                int gc = ccol + n * 16;
                float v = acc[m][n][j];
                if (region == 0) {
                    float r = sigmoidf_(v + br[gc]);
                    RH[(size_t)gr * 256 + gc] = f2bf(r * h[(size_t)gr * 256 + gc]);
                } else if (region == 1) {
                    int c = gc - 256;
                    Z[(size_t)gr * 256 + c] = sigmoidf_(v + bz[c]);
                } else {
                    int c = gc - 512;
                    U[(size_t)gr * 256 + c] = v;
                }
            }
}

// ---------------- CSR gather: X rows (no atomics), writes bf16 ----------------
__global__ void gather_kernel(const unsigned short* __restrict__ P,
                              const int* __restrict__ offs, const int* __restrict__ entries,
                              const float* __restrict__ bias, unsigned short* __restrict__ Xb) {
    int wv = threadIdx.x >> 6, lane = threadIdx.x & 63;
    int slot = blockIdx.x * 4 + wv;             // [0, 2N)
    int dir = slot >> 12, node = slot & 4095;
    const int* o = offs + (size_t)dir * OSTRIDE;
    int beg = o[node], end = o[node + 1];
    const int* ent = entries + (size_t)dir * EE;
    const float4* bias4 = (const float4*)bias;
    float4 acc = {0.f, 0.f, 0.f, 0.f};
    for (int p = beg; p < end; ++p) {
        int e2 = ent[p];
        int row = e2 >> 4, t = e2 & 15;
        ushort4 pv = *(const ushort4*)(P + (size_t)row * 4096 + t * 256 + lane * 4);
        float4 bv = bias4[t * 64 + lane];
        acc.x += bf2f(pv.x) + bv.x;
        acc.y += bf2f(pv.y) + bv.y;
        acc.z += bf2f(pv.z) + bv.z;
        acc.w += bf2f(pv.w) + bv.w;
    }
    ushort4 o4;
    o4.x = f2bf(acc.x); o4.y = f2bf(acc.y); o4.z = f2bf(acc.z); o4.w = f2bf(acc.w);
    int colbase = (dir == 0 ? 256 : 0) + lane * 4;
    *(ushort4*)(Xb + (size_t)node * 768 + colbase) = o4;
}

// ---------------- h update (fused: h, h_bf, Xbf h-slice) ----------------
__global__ void update_h(float* __restrict__ h, const float* __restrict__ Z,
                         const float* __restrict__ U, const float* __restrict__ HH,
                         const float* __restrict__ bh, unsigned short* __restrict__ hbf,
                         unsigned short* __restrict__ Xbf) {
    int idx = blockIdx.x * 256 + threadIdx.x;   // B*N*64, 4 elems each
    int bn = idx >> 6, q = idx & 63;
    float4 z = ((const float4*)Z)[idx];
    float4 u = ((const float4*)U)[idx];
    float4 hh = ((const float4*)HH)[idx];
    float4 hv = ((const float4*)h)[idx];
    float4 bb = ((const float4*)bh)[q];
    float4 hn;
    hn.x = (1.f - z.x) * hv.x + z.x * tanhf(u.x + hh.x + bb.x);
    hn.y = (1.f - z.y) * hv.y + z.y * tanhf(u.y + hh.y + bb.y);
    hn.z = (1.f - z.z) * hv.z + z.z * tanhf(u.z + hh.z + bb.z);
    hn.w = (1.f - z.w) * hv.w + z.w * tanhf(u.w + hh.w + bb.w);
    ((float4*)h)[idx] = hn;
    ushort4 o;
    o.x = f2bf(hn.x); o.y = f2bf(hn.y); o.z = f2bf(hn.z); o.w = f2bf(hn.w);
    ((ushort4*)hbf)[idx] = o;
    ((ushort4*)(Xbf + (size_t)bn * 768 + 512))[q] = o;
}

// ---------------- final attention readout ----------------
__global__ void final_reduce(const float* __restrict__ h, const float* __restrict__ ann,
                             const float* __restrict__ Wa, const float* __restrict__ ba,
                             const float* __restrict__ Wo, const float* __restrict__ bo,
                             float* __restrict__ acc) {
    int wv = threadIdx.x >> 6, lane = threadIdx.x & 63;
    int b = blockIdx.x >> 5;
    int nbase = (blockIdx.x & 31) * 128 + wv * 32;
    float4 wah = ((const float4*)Wa)[lane];
    float4 woh = ((const float4*)Wo)[lane];
    float4 waa = {0, 0, 0, 0}, woa = {0, 0, 0, 0};
    if (lane < 16) {
        waa = ((const float4*)(Wa + 256))[lane];
        woa = ((const float4*)(Wo + 256))[lane];
    }
    float bav = ba[0], bov = bo[0];
    float part = 0.f;
    for (int it = 0; it < 32; ++it) {
        int node = nbase + it;
        float4 hv = ((const float4*)(h + ((size_t)b * NN + node) * DD))[lane];
        float sa = hv.x * wah.x + hv.y * wah.y + hv.z * wah.z + hv.w * wah.w;
        float so = hv.x * woh.x + hv.y * woh.y + hv.z * woh.z + hv.w * woh.w;
        if (lane < 16) {
            float4 av = ((const float4*)(ann + ((size_t)b * NN + node) * ADIM))[lane];
            sa += av.x * waa.x + av.y * waa.y + av.z * waa.z + av.w * waa.w;
            so += av.x * woa.x + av.y * woa.y + av.z * woa.z + av.w * woa.w;
        }
        for (int off = 32; off; off >>= 1) {
            sa += __shfl_down(sa, off);
            so += __shfl_down(so, off);
        }
        if (lane == 0) part += sigmoidf_(sa + bav) * tanhf(so + bov);
    }
    if (lane == 0) atomicAdd(&acc[b], part);
}

__global__ void final_out(const float* __restrict__ acc, float* __restrict__ out) {
    int b = threadIdx.x;
    if (b < BB) out[b] = sigmoidf_(acc[b]);
}

extern "C" void kernel_launch(void* const* d_in, const int* in_sizes, int n_in,
                              void* d_out, int out_size, void* d_ws, size_t ws_size,
                              hipStream_t stream) {
    const int*   ann_id     = (const int*)d_in[0];
    const int*   src        = (const int*)d_in[1];
    const int*   dst        = (const int*)d_in[2];
    const int*   etype      = (const int*)d_in[3];
    const float* edge_embed = (const float*)d_in[4];
    const float* edge_bias  = (const float*)d_in[5];
    const float* type_embed = (const float*)d_in[6];
    const float* Wr = (const float*)d_in[7];
    const float* br = (const float*)d_in[8];
    const float* Wz = (const float*)d_in[9];
    const float* bz = (const float*)d_in[10];
    const float* Wh = (const float*)d_in[11];
    const float* bh = (const float*)d_in[12];
    const float* Wa = (const float*)d_in[13];
    const float* ba = (const float*)d_in[14];
    const float* Wo = (const float*)d_in[15];
    const float* bo = (const float*)d_in[16];
    float* out = (float*)d_out;

    char* base = (char*)d_ws;
    size_t off = 0;
    auto alloc = [&](size_t bytes) { char* p = base + off; off += (bytes + 255) & ~(size_t)255; return p; };
    float* ann  = (float*)alloc((size_t)BB * NN * ADIM * 4);          // 4 MB
    float* h    = (float*)alloc((size_t)BB * NN * DD * 4);            // 16 MB
    float* Z    = (float*)alloc((size_t)BB * NN * DD * 4);            // 16 MB
    float* U    = (float*)alloc((size_t)BB * NN * DD * 4);            // 16 MB
    float* HH   = (float*)alloc((size_t)BB * NN * DD * 4);            // 16 MB
    float* acc  = (float*)alloc(64);
    unsigned short* h_bf   = (unsigned short*)alloc((size_t)BB * NN * DD * 2);   // 8 MB
    unsigned short* W2bf   = (unsigned short*)alloc((size_t)TT * DD * DD * 2);   // 2 MB
    unsigned short* Wcatbf = (unsigned short*)alloc(768 * 768 * 2);
    unsigned short* Whhbf  = (unsigned short*)alloc(256 * 256 * 2);
    unsigned short* P      = (unsigned short*)alloc((size_t)NN * TT * DD * 2);   // 32 MB
    unsigned short* Xbf    = (unsigned short*)alloc((size_t)BB * NN * 768 * 2);  // 24 MB
    unsigned short* RHbf   = (unsigned short*)alloc((size_t)BB * NN * DD * 2);   // 8 MB
    int* counts  = (int*)alloc((size_t)BB * 2 * NN * 4);              // 128 KB
    int* cursor  = (int*)alloc((size_t)BB * 2 * NN * 4);
    int* offsets = (int*)alloc((size_t)BB * 2 * OSTRIDE * 4);
    int* entries = (int*)alloc((size_t)BB * 2 * EE * 4);              // 512 KB
    // total ~143 MB

    // ---- prep (once per call) ----
    init_kernel<<<dim3((BB * NN * 64) / 256), dim3(256), 0, stream>>>(
        ann_id, type_embed, ann, h, h_bf, Xbf);
    conv_f2b4<<<dim3((TT * DD * DD) / 1024), dim3(256), 0, stream>>>(edge_embed, W2bf);
    build_wcat<<<dim3((768 * 768) / 256), dim3(256), 0, stream>>>(Wr, Wz, Wh, Wcatbf);
    build_whh<<<dim3((256 * 256) / 256), dim3(256), 0, stream>>>(Wh, Whhbf);
    hipMemsetAsync(counts, 0, (size_t)BB * 2 * NN * 4, stream);
    count_kernel<<<dim3((BB * EE) / 256), dim3(256), 0, stream>>>(src, dst, counts);
    scan_kernel<<<dim3(BB * 2), dim3(1024), 0, stream>>>(counts, offsets, cursor);
    fill_kernel<<<dim3((BB * EE) / 256), dim3(256), 0, stream>>>(src, dst, etype, cursor, entries);

    for (int s = 0; s < STEPS; ++s) {
        for (int b = 0; b < BB; ++b) {
            gemm_bt<1><<<dim3((NN / 128) * ((TT * DD) / 128)), dim3(256), 0, stream>>>(
                h_bf + (size_t)b * NN * DD, W2bf, P, NN, TT * DD, DD);
            gather_kernel<<<dim3(2 * NN / 4), dim3(256), 0, stream>>>(
                P, offsets + (size_t)b * 2 * OSTRIDE, entries + (size_t)b * 2 * EE,
                edge_bias, Xbf + (size_t)b * NN * 768);
        }
        gemm_rzu<<<dim3(((BB * NN) / 128) * (768 / 128)), dim3(256), 0, stream>>>(
            Xbf, Wcatbf, br, bz, h, RHbf, Z, U);
        gemm_bt<0><<<dim3(((BB * NN) / 128) * (256 / 128)), dim3(256), 0, stream>>>(
            RHbf, Whhbf, HH, BB * NN, 256, 256);
        update_h<<<dim3((BB * NN * 64) / 256), dim3(256), 0, stream>>>(
            h, Z, U, HH, bh, h_bf, Xbf);
    }

    hipMemsetAsync(acc, 0, 64, stream);
    final_reduce<<<dim3(128), dim3(256), 0, stream>>>(h, ann, Wa, ba, Wo, bo, acc);
    final_out<<<dim3(1), dim3(64), 0, stream>>>(acc, out);
}

// Round 6
// 563.542 us; speedup vs baseline: 6.8279x; 1.2870x over previous
//
#include <hip/hip_runtime.h>
#include <cstdint>

#define BB 4
#define NN 4096
#define EE 16384
#define DD 256
#define ADIM 64
#define TT 16
#define HALFE 8
#define STEPS 3
#define OSTRIDE 4160

typedef __attribute__((ext_vector_type(8))) short short8;
typedef __attribute__((ext_vector_type(4))) float f32x4;

__device__ __forceinline__ float sigmoidf_(float x) { return 1.0f / (1.0f + __expf(-x)); }

__device__ __forceinline__ unsigned short f2bf(float x) {
    unsigned u = __float_as_uint(x);
    u += 0x7fffu + ((u >> 16) & 1u);
    return (unsigned short)(u >> 16);
}
__device__ __forceinline__ float bf2f(unsigned short b) {
    return __uint_as_float(((unsigned)b) << 16);
}

// ---------------- init: ann, h, h_bf, Xbf[:,512:768] ----------------
__global__ void init_kernel(const int* __restrict__ ann_id,
                            const float* __restrict__ type_embed,
                            float* __restrict__ ann, float* __restrict__ h,
                            unsigned short* __restrict__ hbf,
                            unsigned short* __restrict__ Xbf) {
    int idx = blockIdx.x * 256 + threadIdx.x;   // B*N*64 threads, 4 elems each
    int bn = idx >> 6, q = idx & 63;
    int id = ann_id[bn];
    float4 v = {0.f, 0.f, 0.f, 0.f};
    if (q < 16) {
        if (id > 0) v = ((const float4*)(type_embed + (size_t)(id - 1) * ADIM))[q];
        ((float4*)(ann + (size_t)bn * ADIM))[q] = v;
    }
    ((float4*)(h + (size_t)bn * DD))[q] = v;
    ushort4 o;
    o.x = f2bf(v.x); o.y = f2bf(v.y); o.z = f2bf(v.z); o.w = f2bf(v.w);
    ((ushort4*)(hbf + (size_t)bn * DD))[q] = o;
    ((ushort4*)(Xbf + (size_t)bn * 768 + 512))[q] = o;
}

// ---------------- fp32 -> bf16, 4 elems/thread ----------------
__global__ void conv_f2b4(const float* __restrict__ in, unsigned short* __restrict__ out) {
    int idx = blockIdx.x * 256 + threadIdx.x;
    float4 v = ((const float4*)in)[idx];
    ushort4 o;
    o.x = f2bf(v.x); o.y = f2bf(v.y); o.z = f2bf(v.z); o.w = f2bf(v.w);
    ((ushort4*)out)[idx] = o;
}

// Wcat_t[c][k] (B^T layout)
__global__ void build_wcat(const float* __restrict__ Wr, const float* __restrict__ Wz,
                           const float* __restrict__ Wh, unsigned short* __restrict__ W) {
    int idx = blockIdx.x * 256 + threadIdx.x;   // 768*768
    int c = idx / 768, k = idx % 768;
    float v;
    if (c < 256)       v = Wr[c * 768 + k];
    else if (c < 512)  v = Wz[(c - 256) * 768 + k];
    else               v = (k < 512) ? Wh[(c - 512) * 768 + k] : 0.f;
    W[idx] = f2bf(v);
}

// Whh_t[i][k] = Wh[i][512+k]
__global__ void build_whh(const float* __restrict__ Wh, unsigned short* __restrict__ W) {
    int idx = blockIdx.x * 256 + threadIdx.x;   // 256*256
    int i = idx / 256, k = idx % 256;
    W[idx] = f2bf(Wh[i * 768 + 512 + k]);
}

// ---------------- CSR build ----------------
__global__ void count_kernel(const int* __restrict__ src, const int* __restrict__ dst,
                             int* __restrict__ counts) {
    int idx = blockIdx.x * 256 + threadIdx.x;   // B*E
    int b = idx >> 14;
    atomicAdd(&counts[(b * 2 + 0) * NN + src[idx]], 1);
    atomicAdd(&counts[(b * 2 + 1) * NN + dst[idx]], 1);
}

__global__ __launch_bounds__(1024) void scan_kernel(const int* __restrict__ counts,
                                                    int* __restrict__ offs,
                                                    int* __restrict__ cursor) {
    __shared__ int lsum[1024];
    int t = threadIdx.x, seg = blockIdx.x;      // 8 segments of 4096
    int4 v = ((const int4*)(counts + (size_t)seg * NN))[t];
    int s1 = v.x + v.y, s2 = s1 + v.z, s3 = s2 + v.w;
    lsum[t] = s3;
    __syncthreads();
    for (int off = 1; off < 1024; off <<= 1) {
        int tmp = (t >= off) ? lsum[t - off] : 0;
        __syncthreads();
        lsum[t] += tmp;
        __syncthreads();
    }
    int base = lsum[t] - s3;
    int* o = offs + (size_t)seg * OSTRIDE;
    o[4 * t] = base; o[4 * t + 1] = base + v.x; o[4 * t + 2] = base + s1; o[4 * t + 3] = base + s2;
    if (t == 1023) o[4096] = lsum[1023];
    int* c = cursor + (size_t)seg * NN;
    c[4 * t] = base; c[4 * t + 1] = base + v.x; c[4 * t + 2] = base + s1; c[4 * t + 3] = base + s2;
}

__global__ void fill_kernel(const int* __restrict__ src, const int* __restrict__ dst,
                            const int* __restrict__ et, int* __restrict__ cursor,
                            int* __restrict__ entries) {
    int idx = blockIdx.x * 256 + threadIdx.x;   // B*E
    int b = idx >> 14;
    int s = src[idx], d = dst[idx], t = et[idx];
    int p0 = atomicAdd(&cursor[(b * 2 + 0) * NN + s], 1);
    entries[(size_t)(b * 2 + 0) * EE + p0] = (d << 4) | t;
    int p1 = atomicAdd(&cursor[(b * 2 + 1) * NN + d], 1);
    entries[(size_t)(b * 2 + 1) * EE + p1] = (s << 4) | (t + 8);
}

// ============ shared GEMM core (m97 structure) ============
// Computes acc via swapped-operand MFMA: lane layout after swap:
//   row(M) = r0 + wr*64 + m*16 + (lane&15)
//   col(N) = c0 + wc*64 + n*16 + ((lane>>4)<<2) + j     (j = acc reg 0..3)
#define GEMM_CORE(A_, Bt_, K_)                                                          \
    const int tid = threadIdx.x;                                                        \
    const int wid = tid >> 6, lane = tid & 63;                                          \
    const int wr = wid >> 1, wc = wid & 1;                                              \
    const int lr = lane & 15, lk = (lane >> 4) << 3;                                    \
    const unsigned short* Ag = A_ + (size_t)(r0 + (tid >> 2)) * K_ + ((tid & 3) << 3);  \
    const unsigned short* Bg = Bt_ + (size_t)(c0 + (tid >> 2)) * K_ + ((tid & 3) << 3); \
    char* AsB = (char*)As + wid * 1024;                                                 \
    char* BsB = (char*)Bs + wid * 1024;                                                 \
    f32x4 acc[4][4] = {};                                                               \
    for (int k0 = 0; k0 < K_; k0 += 32) {                                               \
        _Pragma("unroll")                                                               \
        for (int i = 0; i < 2; ++i) {                                                   \
            __builtin_amdgcn_global_load_lds(                                           \
                (const __attribute__((address_space(1))) void*)(Ag + (size_t)(i * 64) * K_ + k0), \
                (__attribute__((address_space(3))) void*)(AsB + i * 4096), 16, 0, 0);   \
            __builtin_amdgcn_global_load_lds(                                           \
                (const __attribute__((address_space(1))) void*)(Bg + (size_t)(i * 64) * K_ + k0), \
                (__attribute__((address_space(3))) void*)(BsB + i * 4096), 16, 0, 0);   \
        }                                                                               \
        __syncthreads();                                                                \
        short8 af[4], bfv[4];                                                           \
        _Pragma("unroll")                                                               \
        for (int m = 0; m < 4; ++m)                                                     \
            af[m] = *(const short8*)&As[(wr * 64 + m * 16 + lr) * 32 + lk];             \
        _Pragma("unroll")                                                               \
        for (int n = 0; n < 4; ++n)                                                     \
            bfv[n] = *(const short8*)&Bs[(wc * 64 + n * 16 + lr) * 32 + lk];            \
        _Pragma("unroll")                                                               \
        for (int m = 0; m < 4; ++m)                                                     \
            _Pragma("unroll")                                                           \
            for (int n = 0; n < 4; ++n)                                                 \
                acc[m][n] = __builtin_amdgcn_mfma_f32_16x16x32_bf16(bfv[n], af[m], acc[m][n], 0, 0, 0); \
        __syncthreads();                                                                \
    }                                                                                   \
    const int erow = r0 + wr * 64 + (lane & 15);                                        \
    const int ecol = c0 + wc * 64 + ((lane >> 4) << 2);

// ---------------- P GEMM: P[16384,4096] = h_bf @ W2bf^T, bf16 out ----------------
__global__ __launch_bounds__(256) void gemm_p(const unsigned short* __restrict__ A,
                                              const unsigned short* __restrict__ Bt,
                                              unsigned short* __restrict__ C) {
    __shared__ __align__(16) unsigned short As[128 * 32];
    __shared__ __align__(16) unsigned short Bs[128 * 32];
    const int nb = (TT * DD) >> 7;              // 32
    const int bx = blockIdx.x % nb, by = blockIdx.x / nb;
    const int r0 = by << 7, c0 = bx << 7;
    GEMM_CORE(A, Bt, DD)
#pragma unroll
    for (int m = 0; m < 4; ++m)
#pragma unroll
        for (int n = 0; n < 4; ++n) {
            ushort4 o;
            o.x = f2bf(acc[m][n][0]); o.y = f2bf(acc[m][n][1]);
            o.z = f2bf(acc[m][n][2]); o.w = f2bf(acc[m][n][3]);
            *(ushort4*)&C[(size_t)(erow + m * 16) * (TT * DD) + ecol + n * 16] = o;
        }
}

// ---------------- RZU GEMM with fused GRU-gate epilogue ----------------
// C = Xbf[16384,768] @ Wcat_t^T; cols 0:256 -> RH=bf16(sig(v+br)*h),
// 256:512 -> Zb=bf16(sig(v+bz)), 512:768 -> Ub=bf16(v)
__global__ __launch_bounds__(256) void gemm_rzu(const unsigned short* __restrict__ A,
                                                const unsigned short* __restrict__ Bt,
                                                const float* __restrict__ br,
                                                const float* __restrict__ bz,
                                                const float* __restrict__ h,
                                                unsigned short* __restrict__ RH,
                                                unsigned short* __restrict__ Zb,
                                                unsigned short* __restrict__ Ub) {
    __shared__ __align__(16) unsigned short As[128 * 32];
    __shared__ __align__(16) unsigned short Bs[128 * 32];
    const int nb = 6;
    const int bx = blockIdx.x % nb, by = blockIdx.x / nb;
    const int r0 = by << 7, c0 = bx << 7;
    GEMM_CORE(A, Bt, 768)
    const int region = c0 >> 8;
#pragma unroll
    for (int m = 0; m < 4; ++m)
#pragma unroll
        for (int n = 0; n < 4; ++n) {
            int gr = erow + m * 16;
            int gc = ecol + n * 16;
            f32x4 v = acc[m][n];
            if (region == 0) {
                float4 bb = *(const float4*)&br[gc];
                float4 hv = *(const float4*)&h[(size_t)gr * 256 + gc];
                ushort4 o;
                o.x = f2bf(sigmoidf_(v[0] + bb.x) * hv.x);
                o.y = f2bf(sigmoidf_(v[1] + bb.y) * hv.y);
                o.z = f2bf(sigmoidf_(v[2] + bb.z) * hv.z);
                o.w = f2bf(sigmoidf_(v[3] + bb.w) * hv.w);
                *(ushort4*)&RH[(size_t)gr * 256 + gc] = o;
            } else if (region == 1) {
                int c = gc - 256;
                float4 bb = *(const float4*)&bz[c];
                ushort4 o;
                o.x = f2bf(sigmoidf_(v[0] + bb.x));
                o.y = f2bf(sigmoidf_(v[1] + bb.y));
                o.z = f2bf(sigmoidf_(v[2] + bb.z));
                o.w = f2bf(sigmoidf_(v[3] + bb.w));
                *(ushort4*)&Zb[(size_t)gr * 256 + c] = o;
            } else {
                int c = gc - 512;
                ushort4 o;
                o.x = f2bf(v[0]); o.y = f2bf(v[1]); o.z = f2bf(v[2]); o.w = f2bf(v[3]);
                *(ushort4*)&Ub[(size_t)gr * 256 + c] = o;
            }
        }
}

// ---------------- HH GEMM with fused h-update epilogue ----------------
// hh = RHbf @ Whh^T; h = (1-z)*h + z*tanh(u + hh + bh); writes h, h_bf, Xbf h-slice
__global__ __launch_bounds__(256) void gemm_hh(const unsigned short* __restrict__ A,
                                               const unsigned short* __restrict__ Bt,
                                               const unsigned short* __restrict__ Zb,
                                               const unsigned short* __restrict__ Ub,
                                               const float* __restrict__ bh,
                                               float* __restrict__ h,
                                               unsigned short* __restrict__ hbf,
                                               unsigned short* __restrict__ Xbf) {
    __shared__ __align__(16) unsigned short As[128 * 32];
    __shared__ __align__(16) unsigned short Bs[128 * 32];
    const int nb = 2;
    const int bx = blockIdx.x % nb, by = blockIdx.x / nb;
    const int r0 = by << 7, c0 = bx << 7;
    GEMM_CORE(A, Bt, 256)
#pragma unroll
    for (int m = 0; m < 4; ++m)
#pragma unroll
        for (int n = 0; n < 4; ++n) {
            int gr = erow + m * 16;
            int gc = ecol + n * 16;
            size_t base = (size_t)gr * 256 + gc;
            f32x4 v = acc[m][n];
            float4 bb = *(const float4*)&bh[gc];
            float4 hv = *(const float4*)&h[base];
            ushort4 zp = *(const ushort4*)&Zb[base];
            ushort4 up = *(const ushort4*)&Ub[base];
            float4 hn;
            {
                float z = bf2f(zp.x); hn.x = (1.f - z) * hv.x + z * tanhf(bf2f(up.x) + v[0] + bb.x);
            }{
                float z = bf2f(zp.y); hn.y = (1.f - z) * hv.y + z * tanhf(bf2f(up.y) + v[1] + bb.y);
            }{
                float z = bf2f(zp.z); hn.z = (1.f - z) * hv.z + z * tanhf(bf2f(up.z) + v[2] + bb.z);
            }{
                float z = bf2f(zp.w); hn.w = (1.f - z) * hv.w + z * tanhf(bf2f(up.w) + v[3] + bb.w);
            }
            *(float4*)&h[base] = hn;
            ushort4 o;
            o.x = f2bf(hn.x); o.y = f2bf(hn.y); o.z = f2bf(hn.z); o.w = f2bf(hn.w);
            *(ushort4*)&hbf[base] = o;
            *(ushort4*)&Xbf[(size_t)gr * 768 + 512 + gc] = o;
        }
}

// ---------------- CSR gather (all graphs): X rows, no atomics, bf16 out ----------------
__global__ void gather_kernel(const unsigned short* __restrict__ P,
                              const int* __restrict__ offs, const int* __restrict__ entries,
                              const float* __restrict__ bias, unsigned short* __restrict__ Xb) {
    int wv = threadIdx.x >> 6, lane = threadIdx.x & 63;
    int slot = blockIdx.x * 4 + wv;             // [0, B*2*N)
    int b = slot >> 13;
    int dir = (slot >> 12) & 1;
    int node = slot & 4095;
    const int* o = offs + (size_t)(b * 2 + dir) * OSTRIDE;
    int beg = o[node], end = o[node + 1];
    const int* ent = entries + (size_t)(b * 2 + dir) * EE;
    const unsigned short* Pg = P + (size_t)b * NN * (TT * DD);
    const float4* bias4 = (const float4*)bias;
    float4 acc = {0.f, 0.f, 0.f, 0.f};
    for (int p = beg; p < end; ++p) {
        int e2 = ent[p];
        int row = e2 >> 4, t = e2 & 15;
        ushort4 pv = *(const ushort4*)(Pg + (size_t)row * 4096 + t * 256 + lane * 4);
        float4 bv = bias4[t * 64 + lane];
        acc.x += bf2f(pv.x) + bv.x;
        acc.y += bf2f(pv.y) + bv.y;
        acc.z += bf2f(pv.z) + bv.z;
        acc.w += bf2f(pv.w) + bv.w;
    }
    ushort4 o4;
    o4.x = f2bf(acc.x); o4.y = f2bf(acc.y); o4.z = f2bf(acc.z); o4.w = f2bf(acc.w);
    int colbase = (dir == 0 ? 256 : 0) + lane * 4;
    *(ushort4*)(Xb + ((size_t)b * NN + node) * 768 + colbase) = o4;
}

// ---------------- final attention readout ----------------
__global__ void final_reduce(const float* __restrict__ h, const float* __restrict__ ann,
                             const float* __restrict__ Wa, const float* __restrict__ ba,
                             const float* __restrict__ Wo, const float* __restrict__ bo,
                             float* __restrict__ acc) {
    int wv = threadIdx.x >> 6, lane = threadIdx.x & 63;
    int b = blockIdx.x >> 5;
    int nbase = (blockIdx.x & 31) * 128 + wv * 32;
    float4 wah = ((const float4*)Wa)[lane];
    float4 woh = ((const float4*)Wo)[lane];
    float4 waa = {0, 0, 0, 0}, woa = {0, 0, 0, 0};
    if (lane < 16) {
        waa = ((const float4*)(Wa + 256))[lane];
        woa = ((const float4*)(Wo + 256))[lane];
    }
    float bav = ba[0], bov = bo[0];
    float part = 0.f;
    for (int it = 0; it < 32; ++it) {
        int node = nbase + it;
        float4 hv = ((const float4*)(h + ((size_t)b * NN + node) * DD))[lane];
        float sa = hv.x * wah.x + hv.y * wah.y + hv.z * wah.z + hv.w * wah.w;
        float so = hv.x * woh.x + hv.y * woh.y + hv.z * woh.z + hv.w * woh.w;
        if (lane < 16) {
            float4 av = ((const float4*)(ann + ((size_t)b * NN + node) * ADIM))[lane];
            sa += av.x * waa.x + av.y * waa.y + av.z * waa.z + av.w * waa.w;
            so += av.x * woa.x + av.y * woa.y + av.z * woa.z + av.w * woa.w;
        }
        for (int off = 32; off; off >>= 1) {
            sa += __shfl_down(sa, off);
            so += __shfl_down(so, off);
        }
        if (lane == 0) part += sigmoidf_(sa + bav) * tanhf(so + bov);
    }
    if (lane == 0) atomicAdd(&acc[b], part);
}

__global__ void final_out(const float* __restrict__ acc, float* __restrict__ out) {
    int b = threadIdx.x;
    if (b < BB) out[b] = sigmoidf_(acc[b]);
}

extern "C" void kernel_launch(void* const* d_in, const int* in_sizes, int n_in,
                              void* d_out, int out_size, void* d_ws, size_t ws_size,
                              hipStream_t stream) {
    const int*   ann_id     = (const int*)d_in[0];
    const int*   src        = (const int*)d_in[1];
    const int*   dst        = (const int*)d_in[2];
    const int*   etype      = (const int*)d_in[3];
    const float* edge_embed = (const float*)d_in[4];
    const float* edge_bias  = (const float*)d_in[5];
    const float* type_embed = (const float*)d_in[6];
    const float* Wr = (const float*)d_in[7];
    const float* br = (const float*)d_in[8];
    const float* Wz = (const float*)d_in[9];
    const float* bz = (const float*)d_in[10];
    const float* Wh = (const float*)d_in[11];
    const float* bh = (const float*)d_in[12];
    const float* Wa = (const float*)d_in[13];
    const float* ba = (const float*)d_in[14];
    const float* Wo = (const float*)d_in[15];
    const float* bo = (const float*)d_in[16];
    float* out = (float*)d_out;

    char* base = (char*)d_ws;
    size_t off = 0;
    auto alloc = [&](size_t bytes) { char* p = base + off; off += (bytes + 255) & ~(size_t)255; return p; };
    float* ann  = (float*)alloc((size_t)BB * NN * ADIM * 4);          // 4 MB
    float* h    = (float*)alloc((size_t)BB * NN * DD * 4);            // 16 MB
    float* acc  = (float*)alloc(64);
    unsigned short* h_bf   = (unsigned short*)alloc((size_t)BB * NN * DD * 2);   // 8 MB
    unsigned short* W2bf   = (unsigned short*)alloc((size_t)TT * DD * DD * 2);   // 2 MB
    unsigned short* Wcatbf = (unsigned short*)alloc(768 * 768 * 2);
    unsigned short* Whhbf  = (unsigned short*)alloc(256 * 256 * 2);
    unsigned short* P      = (unsigned short*)alloc((size_t)BB * NN * TT * DD * 2); // 128 MB
    unsigned short* Xbf    = (unsigned short*)alloc((size_t)BB * NN * 768 * 2);  // 24 MB
    unsigned short* RHbf   = (unsigned short*)alloc((size_t)BB * NN * DD * 2);   // 8 MB
    unsigned short* Zb     = (unsigned short*)alloc((size_t)BB * NN * DD * 2);   // 8 MB
    unsigned short* Ub     = (unsigned short*)alloc((size_t)BB * NN * DD * 2);   // 8 MB
    int* counts  = (int*)alloc((size_t)BB * 2 * NN * 4);              // 128 KB
    int* cursor  = (int*)alloc((size_t)BB * 2 * NN * 4);
    int* offsets = (int*)alloc((size_t)BB * 2 * OSTRIDE * 4);
    int* entries = (int*)alloc((size_t)BB * 2 * EE * 4);              // 512 KB
    // total ~209 MB

    // ---- prep (once per call) ----
    init_kernel<<<dim3((BB * NN * 64) / 256), dim3(256), 0, stream>>>(
        ann_id, type_embed, ann, h, h_bf, Xbf);
    conv_f2b4<<<dim3((TT * DD * DD) / 1024), dim3(256), 0, stream>>>(edge_embed, W2bf);
    build_wcat<<<dim3((768 * 768) / 256), dim3(256), 0, stream>>>(Wr, Wz, Wh, Wcatbf);
    build_whh<<<dim3((256 * 256) / 256), dim3(256), 0, stream>>>(Wh, Whhbf);
    hipMemsetAsync(counts, 0, (size_t)BB * 2 * NN * 4, stream);
    count_kernel<<<dim3((BB * EE) / 256), dim3(256), 0, stream>>>(src, dst, counts);
    scan_kernel<<<dim3(BB * 2), dim3(1024), 0, stream>>>(counts, offsets, cursor);
    fill_kernel<<<dim3((BB * EE) / 256), dim3(256), 0, stream>>>(src, dst, etype, cursor, entries);

    for (int s = 0; s < STEPS; ++s) {
        // P[16384,4096] = h_bf @ W2^T  (all graphs, one dispatch)
        gemm_p<<<dim3(((BB * NN) / 128) * ((TT * DD) / 128)), dim3(256), 0, stream>>>(
            h_bf, W2bf, P);
        gather_kernel<<<dim3(BB * 2 * NN / 4), dim3(256), 0, stream>>>(
            P, offsets, entries, edge_bias, Xbf);
        gemm_rzu<<<dim3(((BB * NN) / 128) * (768 / 128)), dim3(256), 0, stream>>>(
            Xbf, Wcatbf, br, bz, h, RHbf, Zb, Ub);
        gemm_hh<<<dim3(((BB * NN) / 128) * (256 / 128)), dim3(256), 0, stream>>>(
            RHbf, Whhbf, Zb, Ub, bh, h, h_bf, Xbf);
    }

    hipMemsetAsync(acc, 0, 64, stream);
    final_reduce<<<dim3(128), dim3(256), 0, stream>>>(h, ann, Wa, ba, Wo, bo, acc);
    final_out<<<dim3(1), dim3(64), 0, stream>>>(acc, out);
}

// Round 7
// 514.134 us; speedup vs baseline: 7.4840x; 1.0961x over previous
//
#include <hip/hip_runtime.h>
#include <cstdint>

#define BB 4
#define NN 4096
#define EE 16384
#define DD 256
#define ADIM 64
#define TT 16
#define HALFE 8
#define STEPS 3
#define OSTRIDE 4160
#define MAXTILES 1088            // 131072/128 + 64 pad tiles
#define MAXM (MAXTILES * 128)

typedef __attribute__((ext_vector_type(8))) short short8;
typedef __attribute__((ext_vector_type(4))) float f32x4;

__device__ __forceinline__ float sigmoidf_(float x) { return 1.0f / (1.0f + __expf(-x)); }

__device__ __forceinline__ unsigned short f2bf(float x) {
    unsigned u = __float_as_uint(x);
    u += 0x7fffu + ((u >> 16) & 1u);
    return (unsigned short)(u >> 16);
}
__device__ __forceinline__ float bf2f(unsigned short b) {
    return __uint_as_float(((unsigned)b) << 16);
}

// ---------------- init: ann, h, h_bf, Xbf[:,512:768] ----------------
__global__ void init_kernel(const int* __restrict__ ann_id,
                            const float* __restrict__ type_embed,
                            float* __restrict__ ann, float* __restrict__ h,
                            unsigned short* __restrict__ hbf,
                            unsigned short* __restrict__ Xbf) {
    int idx = blockIdx.x * 256 + threadIdx.x;   // B*N*64 threads, 4 elems each
    int bn = idx >> 6, q = idx & 63;
    int id = ann_id[bn];
    float4 v = {0.f, 0.f, 0.f, 0.f};
    if (q < 16) {
        if (id > 0) v = ((const float4*)(type_embed + (size_t)(id - 1) * ADIM))[q];
        ((float4*)(ann + (size_t)bn * ADIM))[q] = v;
    }
    ((float4*)(h + (size_t)bn * DD))[q] = v;
    ushort4 o;
    o.x = f2bf(v.x); o.y = f2bf(v.y); o.z = f2bf(v.z); o.w = f2bf(v.w);
    ((ushort4*)(hbf + (size_t)bn * DD))[q] = o;
    ((ushort4*)(Xbf + (size_t)bn * 768 + 512))[q] = o;
}

// ---------------- fp32 -> bf16, 4 elems/thread ----------------
__global__ void conv_f2b4(const float* __restrict__ in, unsigned short* __restrict__ out) {
    int idx = blockIdx.x * 256 + threadIdx.x;
    float4 v = ((const float4*)in)[idx];
    ushort4 o;
    o.x = f2bf(v.x); o.y = f2bf(v.y); o.z = f2bf(v.z); o.w = f2bf(v.w);
    ((ushort4*)out)[idx] = o;
}

// Wcat_t[c][k] (B^T layout)
__global__ void build_wcat(const float* __restrict__ Wr, const float* __restrict__ Wz,
                           const float* __restrict__ Wh, unsigned short* __restrict__ W) {
    int idx = blockIdx.x * 256 + threadIdx.x;   // 768*768
    int c = idx / 768, k = idx % 768;
    float v;
    if (c < 256)       v = Wr[c * 768 + k];
    else if (c < 512)  v = Wz[(c - 256) * 768 + k];
    else               v = (k < 512) ? Wh[(c - 512) * 768 + k] : 0.f;
    W[idx] = f2bf(v);
}

// Whh_t[i][k] = Wh[i][512+k]
__global__ void build_whh(const float* __restrict__ Wh, unsigned short* __restrict__ W) {
    int idx = blockIdx.x * 256 + threadIdx.x;   // 256*256
    int i = idx / 256, k = idx % 256;
    W[idx] = f2bf(Wh[i * 768 + 512 + k]);
}

// ---------------- CSR build (node-major, for gather) ----------------
__global__ void count_kernel(const int* __restrict__ src, const int* __restrict__ dst,
                             int* __restrict__ counts) {
    int idx = blockIdx.x * 256 + threadIdx.x;   // B*E
    int b = idx >> 14;
    atomicAdd(&counts[(b * 2 + 0) * NN + src[idx]], 1);
    atomicAdd(&counts[(b * 2 + 1) * NN + dst[idx]], 1);
}

__global__ __launch_bounds__(1024) void scan_kernel(const int* __restrict__ counts,
                                                    int* __restrict__ offs,
                                                    int* __restrict__ cursor) {
    __shared__ int lsum[1024];
    int t = threadIdx.x, seg = blockIdx.x;      // 8 segments of 4096
    int4 v = ((const int4*)(counts + (size_t)seg * NN))[t];
    int s1 = v.x + v.y, s2 = s1 + v.z, s3 = s2 + v.w;
    lsum[t] = s3;
    __syncthreads();
    for (int off = 1; off < 1024; off <<= 1) {
        int tmp = (t >= off) ? lsum[t - off] : 0;
        __syncthreads();
        lsum[t] += tmp;
        __syncthreads();
    }
    int base = lsum[t] - s3;
    int* o = offs + (size_t)seg * OSTRIDE;
    o[4 * t] = base; o[4 * t + 1] = base + v.x; o[4 * t + 2] = base + s1; o[4 * t + 3] = base + s2;
    if (t == 1023) o[4096] = lsum[1023];
    int* c = cursor + (size_t)seg * NN;
    c[4 * t] = base; c[4 * t + 1] = base + v.x; c[4 * t + 2] = base + s1; c[4 * t + 3] = base + s2;
}

// ---------------- type-major counts: bins (b,t) ----------------
__global__ void count2_kernel(const int* __restrict__ et, int* __restrict__ c32) {
    __shared__ int cnt[32];
    int tid = threadIdx.x;
    if (tid < 32) cnt[tid] = 0;
    __syncthreads();
    int idx = blockIdx.x * 256 + tid;           // B*E
    int b = idx >> 14;
    atomicAdd(&cnt[b * 8 + et[idx]], 1);
    __syncthreads();
    if (tid < 32) atomicAdd(&c32[tid], cnt[tid]);
}

// segments seg = b*16 + dir*8 + t, each padded to multiple of 128 rows.
// writes type_cursor[seg] = padded base, tile_type[tile] = dir*8+t.
__global__ void scan2_kernel(const int* __restrict__ c32, int* __restrict__ type_cursor,
                             int* __restrict__ tile_type) {
    if (threadIdx.x != 0 || blockIdx.x != 0) return;
    int off = 0;
    for (int seg = 0; seg < 64; ++seg) {
        int b = seg >> 4, dir = (seg >> 3) & 1, t = seg & 7;
        int cnt = c32[b * 8 + t];
        int t16 = dir * 8 + t;
        type_cursor[seg] = off;
        int ntiles = (cnt + 127) >> 7;
        int tile0 = off >> 7;
        for (int k = 0; k < ntiles; ++k) tile_type[tile0 + k] = t16;
        off += ntiles << 7;
    }
}

// assigns each edge a row p in type-major padded order (idx2[p]=neighbor h-row)
// and writes node-major entries[q] = (p<<4)|t16
__global__ void fill2_kernel(const int* __restrict__ src, const int* __restrict__ dst,
                             const int* __restrict__ et, int* __restrict__ type_cursor,
                             int* __restrict__ node_cursor, int* __restrict__ entries,
                             int* __restrict__ idx2) {
    __shared__ int cnt[64];
    __shared__ int bse[64];
    int tid = threadIdx.x;
    if (tid < 64) cnt[tid] = 0;
    __syncthreads();
    int idx = blockIdx.x * 256 + tid;           // B*E
    int b = idx >> 14;
    int s = src[idx], d = dst[idx], t = et[idx];
    int bin0 = b * 16 + t;                      // dir 0 (out)
    int bin1 = b * 16 + 8 + t;                  // dir 1 (in)
    int r0 = atomicAdd(&cnt[bin0], 1);
    int r1 = atomicAdd(&cnt[bin1], 1);
    __syncthreads();
    if (tid < 64) bse[tid] = atomicAdd(&type_cursor[tid], cnt[tid]);
    __syncthreads();
    int p0 = bse[bin0] + r0;                    // msg row, uses h[d], W[t]
    int p1 = bse[bin1] + r1;                    // msg row, uses h[s], W[t+8]
    idx2[p0] = b * NN + d;
    idx2[p1] = b * NN + s;
    int q0 = atomicAdd(&node_cursor[(b * 2 + 0) * NN + s], 1);
    entries[(size_t)(b * 2 + 0) * EE + q0] = (p0 << 4) | t;
    int q1 = atomicAdd(&node_cursor[(b * 2 + 1) * NN + d], 1);
    entries[(size_t)(b * 2 + 1) * EE + q1] = (p1 << 4) | (t + 8);
}

// ============ shared GEMM core (m97 structure), swapped-operand MFMA ============
//   row(M) = r0 + wr*64 + m*16 + (lane&15)
//   col(N) = c0 + wc*64 + n*16 + ((lane>>4)<<2) + j
#define GEMM_CORE(A_, Bt_, K_)                                                          \
    const int tid = threadIdx.x;                                                        \
    const int wid = tid >> 6, lane = tid & 63;                                          \
    const int wr = wid >> 1, wc = wid & 1;                                              \
    const int lr = lane & 15, lk = (lane >> 4) << 3;                                    \
    const unsigned short* Ag = A_ + (size_t)(r0 + (tid >> 2)) * K_ + ((tid & 3) << 3);  \
    const unsigned short* Bg = Bt_ + (size_t)(c0 + (tid >> 2)) * K_ + ((tid & 3) << 3); \
    char* AsB = (char*)As + wid * 1024;                                                 \
    char* BsB = (char*)Bs + wid * 1024;                                                 \
    f32x4 acc[4][4] = {};                                                               \
    for (int k0 = 0; k0 < K_; k0 += 32) {                                               \
        _Pragma("unroll")                                                               \
        for (int i = 0; i < 2; ++i) {                                                   \
            __builtin_amdgcn_global_load_lds(                                           \
                (const __attribute__((address_space(1))) void*)(Ag + (size_t)(i * 64) * K_ + k0), \
                (__attribute__((address_space(3))) void*)(AsB + i * 4096), 16, 0, 0);   \
            __builtin_amdgcn_global_load_lds(                                           \
                (const __attribute__((address_space(1))) void*)(Bg + (size_t)(i * 64) * K_ + k0), \
                (__attribute__((address_space(3))) void*)(BsB + i * 4096), 16, 0, 0);   \
        }                                                                               \
        __syncthreads();                                                                \
        short8 af[4], bfv[4];                                                           \
        _Pragma("unroll")                                                               \
        for (int m = 0; m < 4; ++m)                                                     \
            af[m] = *(const short8*)&As[(wr * 64 + m * 16 + lr) * 32 + lk];             \
        _Pragma("unroll")                                                               \
        for (int n = 0; n < 4; ++n)                                                     \
            bfv[n] = *(const short8*)&Bs[(wc * 64 + n * 16 + lr) * 32 + lk];            \
        _Pragma("unroll")                                                               \
        for (int m = 0; m < 4; ++m)                                                     \
            _Pragma("unroll")                                                           \
            for (int n = 0; n < 4; ++n)                                                 \
                acc[m][n] = __builtin_amdgcn_mfma_f32_16x16x32_bf16(bfv[n], af[m], acc[m][n], 0, 0, 0); \
        __syncthreads();                                                                \
    }                                                                                   \
    const int erow = r0 + wr * 64 + (lane & 15);                                        \
    const int ecol = c0 + wc * 64 + ((lane >> 4) << 2);

// ---------------- message GEMM: msgs[p] = h_bf[idx2[p]] @ W[tile_type]^T ----------------
__global__ __launch_bounds__(256) void gemm_msgs(const unsigned short* __restrict__ A,
                                                 const unsigned short* __restrict__ W2,
                                                 const int* __restrict__ idx2,
                                                 const int* __restrict__ tile_type,
                                                 unsigned short* __restrict__ C) {
    __shared__ __align__(16) unsigned short As[128 * 32];
    __shared__ __align__(16) unsigned short Bs[128 * 32];
    const int by = blockIdx.x >> 1, bx = blockIdx.x & 1;
    const int t16 = tile_type[by];
    if (t16 < 0) return;
    const int r0 = by << 7, c0 = bx << 7;
    const int tid = threadIdx.x;
    const int wid = tid >> 6, lane = tid & 63;
    const int wr = wid >> 1, wc = wid & 1;
    const int lr = lane & 15, lk = (lane >> 4) << 3;
    const int arow0 = idx2[r0 + (tid >> 2)];
    const int arow1 = idx2[r0 + 64 + (tid >> 2)];
    const unsigned short* Bt = W2 + (size_t)t16 * (DD * DD);
    const unsigned short* Ag0 = A + (size_t)arow0 * DD + ((tid & 3) << 3);
    const unsigned short* Ag1 = A + (size_t)arow1 * DD + ((tid & 3) << 3);
    const unsigned short* Bg = Bt + (size_t)(c0 + (tid >> 2)) * DD + ((tid & 3) << 3);
    char* AsB = (char*)As + wid * 1024;
    char* BsB = (char*)Bs + wid * 1024;
    f32x4 acc[4][4] = {};
    for (int k0 = 0; k0 < DD; k0 += 32) {
        __builtin_amdgcn_global_load_lds(
            (const __attribute__((address_space(1))) void*)(Ag0 + k0),
            (__attribute__((address_space(3))) void*)(AsB), 16, 0, 0);
        __builtin_amdgcn_global_load_lds(
            (const __attribute__((address_space(1))) void*)(Ag1 + k0),
            (__attribute__((address_space(3))) void*)(AsB + 4096), 16, 0, 0);
        __builtin_amdgcn_global_load_lds(
            (const __attribute__((address_space(1))) void*)(Bg + k0),
            (__attribute__((address_space(3))) void*)(BsB), 16, 0, 0);
        __builtin_amdgcn_global_load_lds(
            (const __attribute__((address_space(1))) void*)(Bg + (size_t)64 * DD + k0),
            (__attribute__((address_space(3))) void*)(BsB + 4096), 16, 0, 0);
        __syncthreads();
        short8 af[4], bfv[4];
#pragma unroll
        for (int m = 0; m < 4; ++m)
            af[m] = *(const short8*)&As[(wr * 64 + m * 16 + lr) * 32 + lk];
#pragma unroll
        for (int n = 0; n < 4; ++n)
            bfv[n] = *(const short8*)&Bs[(wc * 64 + n * 16 + lr) * 32 + lk];
#pragma unroll
        for (int m = 0; m < 4; ++m)
#pragma unroll
            for (int n = 0; n < 4; ++n)
                acc[m][n] = __builtin_amdgcn_mfma_f32_16x16x32_bf16(bfv[n], af[m], acc[m][n], 0, 0, 0);
        __syncthreads();
    }
    const int erow = r0 + wr * 64 + (lane & 15);
    const int ecol = c0 + wc * 64 + ((lane >> 4) << 2);
#pragma unroll
    for (int m = 0; m < 4; ++m)
#pragma unroll
        for (int n = 0; n < 4; ++n) {
            ushort4 o;
            o.x = f2bf(acc[m][n][0]); o.y = f2bf(acc[m][n][1]);
            o.z = f2bf(acc[m][n][2]); o.w = f2bf(acc[m][n][3]);
            *(ushort4*)&C[(size_t)(erow + m * 16) * DD + ecol + n * 16] = o;
        }
}

// ---------------- RZU GEMM with fused GRU-gate epilogue ----------------
__global__ __launch_bounds__(256) void gemm_rzu(const unsigned short* __restrict__ A,
                                                const unsigned short* __restrict__ Bt,
                                                const float* __restrict__ br,
                                                const float* __restrict__ bz,
                                                const float* __restrict__ h,
                                                unsigned short* __restrict__ RH,
                                                unsigned short* __restrict__ Zb,
                                                unsigned short* __restrict__ Ub) {
    __shared__ __align__(16) unsigned short As[128 * 32];
    __shared__ __align__(16) unsigned short Bs[128 * 32];
    const int nb = 6;
    const int bx = blockIdx.x % nb, by = blockIdx.x / nb;
    const int r0 = by << 7, c0 = bx << 7;
    GEMM_CORE(A, Bt, 768)
    const int region = c0 >> 8;
#pragma unroll
    for (int m = 0; m < 4; ++m)
#pragma unroll
        for (int n = 0; n < 4; ++n) {
            int gr = erow + m * 16;
            int gc = ecol + n * 16;
            f32x4 v = acc[m][n];
            if (region == 0) {
                float4 bb = *(const float4*)&br[gc];
                float4 hv = *(const float4*)&h[(size_t)gr * 256 + gc];
                ushort4 o;
                o.x = f2bf(sigmoidf_(v[0] + bb.x) * hv.x);
                o.y = f2bf(sigmoidf_(v[1] + bb.y) * hv.y);
                o.z = f2bf(sigmoidf_(v[2] + bb.z) * hv.z);
                o.w = f2bf(sigmoidf_(v[3] + bb.w) * hv.w);
                *(ushort4*)&RH[(size_t)gr * 256 + gc] = o;
            } else if (region == 1) {
                int c = gc - 256;
                float4 bb = *(const float4*)&bz[c];
                ushort4 o;
                o.x = f2bf(sigmoidf_(v[0] + bb.x));
                o.y = f2bf(sigmoidf_(v[1] + bb.y));
                o.z = f2bf(sigmoidf_(v[2] + bb.z));
                o.w = f2bf(sigmoidf_(v[3] + bb.w));
                *(ushort4*)&Zb[(size_t)gr * 256 + c] = o;
            } else {
                int c = gc - 512;
                ushort4 o;
                o.x = f2bf(v[0]); o.y = f2bf(v[1]); o.z = f2bf(v[2]); o.w = f2bf(v[3]);
                *(ushort4*)&Ub[(size_t)gr * 256 + c] = o;
            }
        }
}

// ---------------- HH GEMM with fused h-update epilogue ----------------
__global__ __launch_bounds__(256) void gemm_hh(const unsigned short* __restrict__ A,
                                               const unsigned short* __restrict__ Bt,
                                               const unsigned short* __restrict__ Zb,
                                               const unsigned short* __restrict__ Ub,
                                               const float* __restrict__ bh,
                                               float* __restrict__ h,
                                               unsigned short* __restrict__ hbf,
                                               unsigned short* __restrict__ Xbf) {
    __shared__ __align__(16) unsigned short As[128 * 32];
    __shared__ __align__(16) unsigned short Bs[128 * 32];
    const int nb = 2;
    const int bx = blockIdx.x % nb, by = blockIdx.x / nb;
    const int r0 = by << 7, c0 = bx << 7;
    GEMM_CORE(A, Bt, 256)
#pragma unroll
    for (int m = 0; m < 4; ++m)
#pragma unroll
        for (int n = 0; n < 4; ++n) {
            int gr = erow + m * 16;
            int gc = ecol + n * 16;
            size_t base = (size_t)gr * 256 + gc;
            f32x4 v = acc[m][n];
            float4 bb = *(const float4*)&bh[gc];
            float4 hv = *(const float4*)&h[base];
            ushort4 zp = *(const ushort4*)&Zb[base];
            ushort4 up = *(const ushort4*)&Ub[base];
            float4 hn;
            {
                float z = bf2f(zp.x); hn.x = (1.f - z) * hv.x + z * tanhf(bf2f(up.x) + v[0] + bb.x);
            }{
                float z = bf2f(zp.y); hn.y = (1.f - z) * hv.y + z * tanhf(bf2f(up.y) + v[1] + bb.y);
            }{
                float z = bf2f(zp.z); hn.z = (1.f - z) * hv.z + z * tanhf(bf2f(up.z) + v[2] + bb.z);
            }{
                float z = bf2f(zp.w); hn.w = (1.f - z) * hv.w + z * tanhf(bf2f(up.w) + v[3] + bb.w);
            }
            *(float4*)&h[base] = hn;
            ushort4 o;
            o.x = f2bf(hn.x); o.y = f2bf(hn.y); o.z = f2bf(hn.z); o.w = f2bf(hn.w);
            *(ushort4*)&hbf[base] = o;
            *(ushort4*)&Xbf[(size_t)gr * 768 + 512 + gc] = o;
        }
}

// ---------------- CSR gather: sum message rows per (b,dir,node), bf16 out ----------------
__global__ void gather2_kernel(const unsigned short* __restrict__ msgs,
                               const int* __restrict__ offs, const int* __restrict__ entries,
                               const float* __restrict__ bias, unsigned short* __restrict__ Xb) {
    int wv = threadIdx.x >> 6, lane = threadIdx.x & 63;
    int slot = blockIdx.x * 4 + wv;             // [0, B*2*N)
    int b = slot >> 13;
    int dir = (slot >> 12) & 1;
    int node = slot & 4095;
    const int* o = offs + (size_t)(b * 2 + dir) * OSTRIDE;
    int beg = o[node], end = o[node + 1];
    const int* ent = entries + (size_t)(b * 2 + dir) * EE;
    const float4* bias4 = (const float4*)bias;
    float4 acc = {0.f, 0.f, 0.f, 0.f};
    for (int p = beg; p < end; ++p) {
        int e2 = ent[p];
        int row = e2 >> 4, t = e2 & 15;
        ushort4 pv = *(const ushort4*)(msgs + (size_t)row * DD + lane * 4);
        float4 bv = bias4[t * 64 + lane];
        acc.x += bf2f(pv.x) + bv.x;
        acc.y += bf2f(pv.y) + bv.y;
        acc.z += bf2f(pv.z) + bv.z;
        acc.w += bf2f(pv.w) + bv.w;
    }
    ushort4 o4;
    o4.x = f2bf(acc.x); o4.y = f2bf(acc.y); o4.z = f2bf(acc.z); o4.w = f2bf(acc.w);
    int colbase = (dir == 0 ? 256 : 0) + lane * 4;
    *(ushort4*)(Xb + ((size_t)b * NN + node) * 768 + colbase) = o4;
}

// ---------------- final attention readout ----------------
__global__ void final_reduce(const float* __restrict__ h, const float* __restrict__ ann,
                             const float* __restrict__ Wa, const float* __restrict__ ba,
                             const float* __restrict__ Wo, const float* __restrict__ bo,
                             float* __restrict__ acc) {
    int wv = threadIdx.x >> 6, lane = threadIdx.x & 63;
    int b = blockIdx.x >> 5;
    int nbase = (blockIdx.x & 31) * 128 + wv * 32;
    float4 wah = ((const float4*)Wa)[lane];
    float4 woh = ((const float4*)Wo)[lane];
    float4 waa = {0, 0, 0, 0}, woa = {0, 0, 0, 0};
    if (lane < 16) {
        waa = ((const float4*)(Wa + 256))[lane];
        woa = ((const float4*)(Wo + 256))[lane];
    }
    float bav = ba[0], bov = bo[0];
    float part = 0.f;
    for (int it = 0; it < 32; ++it) {
        int node = nbase + it;
        float4 hv = ((const float4*)(h + ((size_t)b * NN + node) * DD))[lane];
        float sa = hv.x * wah.x + hv.y * wah.y + hv.z * wah.z + hv.w * wah.w;
        float so = hv.x * woh.x + hv.y * woh.y + hv.z * woh.z + hv.w * woh.w;
        if (lane < 16) {
            float4 av = ((const float4*)(ann + ((size_t)b * NN + node) * ADIM))[lane];
            sa += av.x * waa.x + av.y * waa.y + av.z * waa.z + av.w * waa.w;
            so += av.x * woa.x + av.y * woa.y + av.z * woa.z + av.w * woa.w;
        }
        for (int off = 32; off; off >>= 1) {
            sa += __shfl_down(sa, off);
            so += __shfl_down(so, off);
        }
        if (lane == 0) part += sigmoidf_(sa + bav) * tanhf(so + bov);
    }
    if (lane == 0) atomicAdd(&acc[b], part);
}

__global__ void final_out(const float* __restrict__ acc, float* __restrict__ out) {
    int b = threadIdx.x;
    if (b < BB) out[b] = sigmoidf_(acc[b]);
}

extern "C" void kernel_launch(void* const* d_in, const int* in_sizes, int n_in,
                              void* d_out, int out_size, void* d_ws, size_t ws_size,
                              hipStream_t stream) {
    const int*   ann_id     = (const int*)d_in[0];
    const int*   src        = (const int*)d_in[1];
    const int*   dst        = (const int*)d_in[2];
    const int*   etype      = (const int*)d_in[3];
    const float* edge_embed = (const float*)d_in[4];
    const float* edge_bias  = (const float*)d_in[5];
    const float* type_embed = (const float*)d_in[6];
    const float* Wr = (const float*)d_in[7];
    const float* br = (const float*)d_in[8];
    const float* Wz = (const float*)d_in[9];
    const float* bz = (const float*)d_in[10];
    const float* Wh = (const float*)d_in[11];
    const float* bh = (const float*)d_in[12];
    const float* Wa = (const float*)d_in[13];
    const float* ba = (const float*)d_in[14];
    const float* Wo = (const float*)d_in[15];
    const float* bo = (const float*)d_in[16];
    float* out = (float*)d_out;

    char* base = (char*)d_ws;
    size_t off = 0;
    auto alloc = [&](size_t bytes) { char* p = base + off; off += (bytes + 255) & ~(size_t)255; return p; };
    float* ann  = (float*)alloc((size_t)BB * NN * ADIM * 4);          // 4 MB
    float* h    = (float*)alloc((size_t)BB * NN * DD * 4);            // 16 MB
    float* acc  = (float*)alloc(64);
    unsigned short* h_bf   = (unsigned short*)alloc((size_t)BB * NN * DD * 2);   // 8 MB
    unsigned short* W2bf   = (unsigned short*)alloc((size_t)TT * DD * DD * 2);   // 2 MB
    unsigned short* Wcatbf = (unsigned short*)alloc(768 * 768 * 2);
    unsigned short* Whhbf  = (unsigned short*)alloc(256 * 256 * 2);
    unsigned short* msgs   = (unsigned short*)alloc((size_t)MAXM * DD * 2);      // 71 MB
    unsigned short* Xbf    = (unsigned short*)alloc((size_t)BB * NN * 768 * 2);  // 24 MB
    unsigned short* RHbf   = (unsigned short*)alloc((size_t)BB * NN * DD * 2);   // 8 MB
    unsigned short* Zb     = (unsigned short*)alloc((size_t)BB * NN * DD * 2);   // 8 MB
    unsigned short* Ub     = (unsigned short*)alloc((size_t)BB * NN * DD * 2);   // 8 MB
    int* counts  = (int*)alloc((size_t)BB * 2 * NN * 4);              // 128 KB
    int* cursor  = (int*)alloc((size_t)BB * 2 * NN * 4);
    int* offsets = (int*)alloc((size_t)BB * 2 * OSTRIDE * 4);
    int* entries = (int*)alloc((size_t)BB * 2 * EE * 4);              // 512 KB
    int* c32     = (int*)alloc(32 * 4);
    int* tcur    = (int*)alloc(64 * 4);
    int* ttype   = (int*)alloc(MAXTILES * 4);
    int* idx2    = (int*)alloc((size_t)MAXM * 4);                     // 557 KB
    // total ~151 MB

    // ---- prep (once per call) ----
    init_kernel<<<dim3((BB * NN * 64) / 256), dim3(256), 0, stream>>>(
        ann_id, type_embed, ann, h, h_bf, Xbf);
    conv_f2b4<<<dim3((TT * DD * DD) / 1024), dim3(256), 0, stream>>>(edge_embed, W2bf);
    build_wcat<<<dim3((768 * 768) / 256), dim3(256), 0, stream>>>(Wr, Wz, Wh, Wcatbf);
    build_whh<<<dim3((256 * 256) / 256), dim3(256), 0, stream>>>(Wh, Whhbf);
    hipMemsetAsync(counts, 0, (size_t)BB * 2 * NN * 4, stream);
    hipMemsetAsync(c32, 0, 32 * 4, stream);
    hipMemsetAsync(ttype, 0xFF, MAXTILES * 4, stream);
    hipMemsetAsync(idx2, 0, (size_t)MAXM * 4, stream);
    count_kernel<<<dim3((BB * EE) / 256), dim3(256), 0, stream>>>(src, dst, counts);
    count2_kernel<<<dim3((BB * EE) / 256), dim3(256), 0, stream>>>(etype, c32);
    scan_kernel<<<dim3(BB * 2), dim3(1024), 0, stream>>>(counts, offsets, cursor);
    scan2_kernel<<<dim3(1), dim3(64), 0, stream>>>(c32, tcur, ttype);
    fill2_kernel<<<dim3((BB * EE) / 256), dim3(256), 0, stream>>>(
        src, dst, etype, tcur, cursor, entries, idx2);

    for (int s = 0; s < STEPS; ++s) {
        gemm_msgs<<<dim3(MAXTILES * 2), dim3(256), 0, stream>>>(
            h_bf, W2bf, idx2, ttype, msgs);
        gather2_kernel<<<dim3(BB * 2 * NN / 4), dim3(256), 0, stream>>>(
            msgs, offsets, entries, edge_bias, Xbf);
        gemm_rzu<<<dim3(((BB * NN) / 128) * (768 / 128)), dim3(256), 0, stream>>>(
            Xbf, Wcatbf, br, bz, h, RHbf, Zb, Ub);
        gemm_hh<<<dim3(((BB * NN) / 128) * (256 / 128)), dim3(256), 0, stream>>>(
            RHbf, Whhbf, Zb, Ub, bh, h, h_bf, Xbf);
    }

    hipMemsetAsync(acc, 0, 64, stream);
    final_reduce<<<dim3(128), dim3(256), 0, stream>>>(h, ann, Wa, ba, Wo, bo, acc);
    final_out<<<dim3(1), dim3(64), 0, stream>>>(acc, out);
}

// Round 8
// 441.160 us; speedup vs baseline: 8.7220x; 1.1654x over previous
//
#include <hip/hip_runtime.h>
#include <cstdint>

#define BB 4
#define NN 4096
#define EE 16384
#define DD 256
#define ADIM 64
#define TT 16
#define HALFE 8
#define STEPS 3
#define OSTRIDE 4160
#define MAXTILES 1088            // 131072/128 + 64 pad tiles
#define MAXM (MAXTILES * 128)

typedef __attribute__((ext_vector_type(8))) short short8;
typedef __attribute__((ext_vector_type(4))) float f32x4;

__device__ __forceinline__ float sigmoidf_(float x) { return 1.0f / (1.0f + __expf(-x)); }

__device__ __forceinline__ unsigned short f2bf(float x) {
    unsigned u = __float_as_uint(x);
    u += 0x7fffu + ((u >> 16) & 1u);
    return (unsigned short)(u >> 16);
}
__device__ __forceinline__ float bf2f(unsigned short b) {
    return __uint_as_float(((unsigned)b) << 16);
}

// ---------------- init: ann, h, h_bf, Xbf[:,512:768] ----------------
__global__ void init_kernel(const int* __restrict__ ann_id,
                            const float* __restrict__ type_embed,
                            float* __restrict__ ann, float* __restrict__ h,
                            unsigned short* __restrict__ hbf,
                            unsigned short* __restrict__ Xbf) {
    int idx = blockIdx.x * 256 + threadIdx.x;   // B*N*64 threads, 4 elems each
    int bn = idx >> 6, q = idx & 63;
    int id = ann_id[bn];
    float4 v = {0.f, 0.f, 0.f, 0.f};
    if (q < 16) {
        if (id > 0) v = ((const float4*)(type_embed + (size_t)(id - 1) * ADIM))[q];
        ((float4*)(ann + (size_t)bn * ADIM))[q] = v;
    }
    ((float4*)(h + (size_t)bn * DD))[q] = v;
    ushort4 o;
    o.x = f2bf(v.x); o.y = f2bf(v.y); o.z = f2bf(v.z); o.w = f2bf(v.w);
    ((ushort4*)(hbf + (size_t)bn * DD))[q] = o;
    ((ushort4*)(Xbf + (size_t)bn * 768 + 512))[q] = o;
}

// ---------------- fp32 -> bf16, 4 elems/thread ----------------
__global__ void conv_f2b4(const float* __restrict__ in, unsigned short* __restrict__ out) {
    int idx = blockIdx.x * 256 + threadIdx.x;
    float4 v = ((const float4*)in)[idx];
    ushort4 o;
    o.x = f2bf(v.x); o.y = f2bf(v.y); o.z = f2bf(v.z); o.w = f2bf(v.w);
    ((ushort4*)out)[idx] = o;
}

// Wcat_t[c][k] (B^T layout)
__global__ void build_wcat(const float* __restrict__ Wr, const float* __restrict__ Wz,
                           const float* __restrict__ Wh, unsigned short* __restrict__ W) {
    int idx = blockIdx.x * 256 + threadIdx.x;   // 768*768
    int c = idx / 768, k = idx % 768;
    float v;
    if (c < 256)       v = Wr[c * 768 + k];
    else if (c < 512)  v = Wz[(c - 256) * 768 + k];
    else               v = (k < 512) ? Wh[(c - 512) * 768 + k] : 0.f;
    W[idx] = f2bf(v);
}

// Whh_t[i][k] = Wh[i][512+k]
__global__ void build_whh(const float* __restrict__ Wh, unsigned short* __restrict__ W) {
    int idx = blockIdx.x * 256 + threadIdx.x;   // 256*256
    int i = idx / 256, k = idx % 256;
    W[idx] = f2bf(Wh[i * 768 + 512 + k]);
}

// ---------------- CSR build (node-major, for gather) ----------------
__global__ void count_kernel(const int* __restrict__ src, const int* __restrict__ dst,
                             int* __restrict__ counts) {
    int idx = blockIdx.x * 256 + threadIdx.x;   // B*E
    int b = idx >> 14;
    atomicAdd(&counts[(b * 2 + 0) * NN + src[idx]], 1);
    atomicAdd(&counts[(b * 2 + 1) * NN + dst[idx]], 1);
}

__global__ __launch_bounds__(1024) void scan_kernel(const int* __restrict__ counts,
                                                    int* __restrict__ offs,
                                                    int* __restrict__ cursor) {
    __shared__ int lsum[1024];
    int t = threadIdx.x, seg = blockIdx.x;      // 8 segments of 4096
    int4 v = ((const int4*)(counts + (size_t)seg * NN))[t];
    int s1 = v.x + v.y, s2 = s1 + v.z, s3 = s2 + v.w;
    lsum[t] = s3;
    __syncthreads();
    for (int off = 1; off < 1024; off <<= 1) {
        int tmp = (t >= off) ? lsum[t - off] : 0;
        __syncthreads();
        lsum[t] += tmp;
        __syncthreads();
    }
    int base = lsum[t] - s3;
    int* o = offs + (size_t)seg * OSTRIDE;
    o[4 * t] = base; o[4 * t + 1] = base + v.x; o[4 * t + 2] = base + s1; o[4 * t + 3] = base + s2;
    if (t == 1023) o[4096] = lsum[1023];
    int* c = cursor + (size_t)seg * NN;
    c[4 * t] = base; c[4 * t + 1] = base + v.x; c[4 * t + 2] = base + s1; c[4 * t + 3] = base + s2;
}

// ---------------- type-major counts: bins (b,t) ----------------
__global__ void count2_kernel(const int* __restrict__ et, int* __restrict__ c32) {
    __shared__ int cnt[32];
    int tid = threadIdx.x;
    if (tid < 32) cnt[tid] = 0;
    __syncthreads();
    int idx = blockIdx.x * 256 + tid;           // B*E
    int b = idx >> 14;
    atomicAdd(&cnt[b * 8 + et[idx]], 1);
    __syncthreads();
    if (tid < 32) atomicAdd(&c32[tid], cnt[tid]);
}

// segments seg = b*16 + dir*8 + t, each padded to multiple of 128 rows (parallel).
__global__ void scan2_kernel(const int* __restrict__ c32, int* __restrict__ type_cursor,
                             int* __restrict__ tile_type) {
    __shared__ int pad[64];
    int t = threadIdx.x;                        // 0..63
    int b = t >> 4, dir = (t >> 3) & 1, tt = t & 7;
    int cnt = c32[b * 8 + tt];
    int padded = ((cnt + 127) >> 7) << 7;
    pad[t] = padded;
    __syncthreads();
    int off = 0;
    for (int k = 0; k < t; ++k) off += pad[k];
    type_cursor[t] = off;
    int t16 = dir * 8 + tt;
    int tile0 = off >> 7;
    for (int k = 0; k < (padded >> 7); ++k) tile_type[tile0 + k] = t16;
}

// assigns each edge a row p in type-major padded order (idx2[p]=neighbor h-row)
// and writes node-major entries[q] = (p<<4)|t16
__global__ void fill2_kernel(const int* __restrict__ src, const int* __restrict__ dst,
                             const int* __restrict__ et, int* __restrict__ type_cursor,
                             int* __restrict__ node_cursor, int* __restrict__ entries,
                             int* __restrict__ idx2) {
    __shared__ int cnt[64];
    __shared__ int bse[64];
    int tid = threadIdx.x;
    if (tid < 64) cnt[tid] = 0;
    __syncthreads();
    int idx = blockIdx.x * 256 + tid;           // B*E
    int b = idx >> 14;
    int s = src[idx], d = dst[idx], t = et[idx];
    int bin0 = b * 16 + t;                      // dir 0 (out)
    int bin1 = b * 16 + 8 + t;                  // dir 1 (in)
    int r0 = atomicAdd(&cnt[bin0], 1);
    int r1 = atomicAdd(&cnt[bin1], 1);
    __syncthreads();
    if (tid < 64) bse[tid] = atomicAdd(&type_cursor[tid], cnt[tid]);
    __syncthreads();
    int p0 = bse[bin0] + r0;                    // msg row, uses h[d], W[t]
    int p1 = bse[bin1] + r1;                    // msg row, uses h[s], W[t+8]
    idx2[p0] = b * NN + d;
    idx2[p1] = b * NN + s;
    int q0 = atomicAdd(&node_cursor[(b * 2 + 0) * NN + s], 1);
    entries[(size_t)(b * 2 + 0) * EE + q0] = (p0 << 4) | t;
    int q1 = atomicAdd(&node_cursor[(b * 2 + 1) * NN + d], 1);
    entries[(size_t)(b * 2 + 1) * EE + q1] = (p1 << 4) | (t + 8);
}

// ============ BK=64 GEMM core, both-sides XOR swizzle, swapped-operand MFMA ============
// LDS tile [128 rows][64 cols] bf16 (16 KB). LDS chunk (row,k) holds global chunk
// (row, k ^ (row&7)); staging source col = ((lane&7)^(lane>>3))*8 (per-lane const);
// read chunk = (kk*4+hi) ^ (lane&7). Output layout (swapped MFMA):
//   row(M) = r0 + wr*64 + m*16 + (lane&15);  col(N) = c0 + wc*64 + n*16 + (lane>>4)*4 + j
#define GEMM_CORE64(A_, Bt_, K_)                                                        \
    const int tid = threadIdx.x;                                                        \
    const int wv = tid >> 6, lane = tid & 63;                                           \
    const int wr = wv >> 1, wc = wv & 1;                                                \
    const int lr = lane & 15, hi = lane >> 4, rx = lane & 7;                            \
    const int srow = wv * 8 + (lane >> 3);                                              \
    const int scol = ((lane & 7) ^ (lane >> 3)) << 3;                                   \
    const unsigned short* Ag = A_ + (size_t)(r0 + srow) * K_ + scol;                    \
    const unsigned short* Bg = Bt_ + (size_t)(c0 + srow) * K_ + scol;                   \
    char* AsW = (char*)As + wv * 1024;                                                  \
    char* BsW = (char*)Bs + wv * 1024;                                                  \
    f32x4 acc[4][4] = {};                                                               \
    for (int k0 = 0; k0 < K_; k0 += 64) {                                               \
        _Pragma("unroll")                                                               \
        for (int i = 0; i < 4; ++i) {                                                   \
            __builtin_amdgcn_global_load_lds(                                           \
                (const __attribute__((address_space(1))) void*)(Ag + (size_t)(i * 32) * K_ + k0), \
                (__attribute__((address_space(3))) void*)(AsW + i * 4096), 16, 0, 0);   \
            __builtin_amdgcn_global_load_lds(                                           \
                (const __attribute__((address_space(1))) void*)(Bg + (size_t)(i * 32) * K_ + k0), \
                (__attribute__((address_space(3))) void*)(BsW + i * 4096), 16, 0, 0);   \
        }                                                                               \
        __syncthreads();                                                                \
        _Pragma("unroll")                                                               \
        for (int kk = 0; kk < 2; ++kk) {                                                \
            short8 af[4], bfv[4];                                                       \
            _Pragma("unroll")                                                           \
            for (int m = 0; m < 4; ++m) {                                               \
                int R = wr * 64 + m * 16 + lr;                                          \
                af[m] = *(const short8*)((const char*)As + R * 128 + (((kk * 4 + hi) ^ rx) << 4)); \
            }                                                                           \
            _Pragma("unroll")                                                           \
            for (int n = 0; n < 4; ++n) {                                               \
                int R = wc * 64 + n * 16 + lr;                                          \
                bfv[n] = *(const short8*)((const char*)Bs + R * 128 + (((kk * 4 + hi) ^ rx) << 4)); \
            }                                                                           \
            _Pragma("unroll")                                                           \
            for (int m = 0; m < 4; ++m)                                                 \
                _Pragma("unroll")                                                       \
                for (int n = 0; n < 4; ++n)                                             \
                    acc[m][n] = __builtin_amdgcn_mfma_f32_16x16x32_bf16(bfv[n], af[m], acc[m][n], 0, 0, 0); \
        }                                                                               \
        __syncthreads();                                                                \
    }                                                                                   \
    const int erow = r0 + wr * 64 + lr;                                                 \
    const int ecol = c0 + wc * 64 + (hi << 2);

// ---------------- message GEMM: msgs[p] = h_bf[idx2[p]] @ W[tile_type]^T ----------------
__global__ __launch_bounds__(256) void gemm_msgs(const unsigned short* __restrict__ A,
                                                 const unsigned short* __restrict__ W2,
                                                 const int* __restrict__ idx2,
                                                 const int* __restrict__ tile_type,
                                                 unsigned short* __restrict__ C) {
    __shared__ __align__(16) unsigned short As[128 * 64];
    __shared__ __align__(16) unsigned short Bs[128 * 64];
    const int bid = blockIdx.x;
    const int wg = (bid & 7) * (MAXTILES * 2 / 8) + (bid >> 3);   // XCD-chunked
    const int by = wg >> 1, bx = wg & 1;
    const int t16 = tile_type[by];
    if (t16 < 0) return;
    const int r0 = by << 7, c0 = bx << 7;
    const int tid = threadIdx.x;
    const int wv = tid >> 6, lane = tid & 63;
    const int wr = wv >> 1, wc = wv & 1;
    const int lr = lane & 15, hi = lane >> 4, rx = lane & 7;
    const int srow = wv * 8 + (lane >> 3);
    const int scol = ((lane & 7) ^ (lane >> 3)) << 3;
    int ar[4];
#pragma unroll
    for (int i = 0; i < 4; ++i) ar[i] = idx2[r0 + srow + i * 32];
    const unsigned short* Bt = W2 + (size_t)t16 * (DD * DD);
    const unsigned short* Bg = Bt + (size_t)(c0 + srow) * DD + scol;
    char* AsW = (char*)As + wv * 1024;
    char* BsW = (char*)Bs + wv * 1024;
    f32x4 acc[4][4] = {};
    for (int k0 = 0; k0 < DD; k0 += 64) {
#pragma unroll
        for (int i = 0; i < 4; ++i) {
            __builtin_amdgcn_global_load_lds(
                (const __attribute__((address_space(1))) void*)(A + (size_t)ar[i] * DD + scol + k0),
                (__attribute__((address_space(3))) void*)(AsW + i * 4096), 16, 0, 0);
            __builtin_amdgcn_global_load_lds(
                (const __attribute__((address_space(1))) void*)(Bg + (size_t)(i * 32) * DD + k0),
                (__attribute__((address_space(3))) void*)(BsW + i * 4096), 16, 0, 0);
        }
        __syncthreads();
#pragma unroll
        for (int kk = 0; kk < 2; ++kk) {
            short8 af[4], bfv[4];
#pragma unroll
            for (int m = 0; m < 4; ++m) {
                int R = wr * 64 + m * 16 + lr;
                af[m] = *(const short8*)((const char*)As + R * 128 + (((kk * 4 + hi) ^ rx) << 4));
            }
#pragma unroll
            for (int n = 0; n < 4; ++n) {
                int R = wc * 64 + n * 16 + lr;
                bfv[n] = *(const short8*)((const char*)Bs + R * 128 + (((kk * 4 + hi) ^ rx) << 4));
            }
#pragma unroll
            for (int m = 0; m < 4; ++m)
#pragma unroll
                for (int n = 0; n < 4; ++n)
                    acc[m][n] = __builtin_amdgcn_mfma_f32_16x16x32_bf16(bfv[n], af[m], acc[m][n], 0, 0, 0);
        }
        __syncthreads();
    }
    const int erow = r0 + wr * 64 + lr;
    const int ecol = c0 + wc * 64 + (hi << 2);
#pragma unroll
    for (int m = 0; m < 4; ++m)
#pragma unroll
        for (int n = 0; n < 4; ++n) {
            ushort4 o;
            o.x = f2bf(acc[m][n][0]); o.y = f2bf(acc[m][n][1]);
            o.z = f2bf(acc[m][n][2]); o.w = f2bf(acc[m][n][3]);
            *(ushort4*)&C[(size_t)(erow + m * 16) * DD + ecol + n * 16] = o;
        }
}

// ---------------- RZU GEMM with fused GRU-gate epilogue ----------------
__global__ __launch_bounds__(256) void gemm_rzu(const unsigned short* __restrict__ A,
                                                const unsigned short* __restrict__ Bt,
                                                const float* __restrict__ br,
                                                const float* __restrict__ bz,
                                                const float* __restrict__ h,
                                                unsigned short* __restrict__ RH,
                                                unsigned short* __restrict__ Zb,
                                                unsigned short* __restrict__ Ub) {
    __shared__ __align__(16) unsigned short As[128 * 64];
    __shared__ __align__(16) unsigned short Bs[128 * 64];
    const int bid = blockIdx.x;
    const int wg = (bid & 7) * 96 + (bid >> 3);   // nwg=768, XCD-chunked
    const int bx = wg % 6, by = wg / 6;
    const int r0 = by << 7, c0 = bx << 7;
    GEMM_CORE64(A, Bt, 768)
    const int region = c0 >> 8;
#pragma unroll
    for (int m = 0; m < 4; ++m)
#pragma unroll
        for (int n = 0; n < 4; ++n) {
            int gr = erow + m * 16;
            int gc = ecol + n * 16;
            f32x4 v = acc[m][n];
            if (region == 0) {
                float4 bb = *(const float4*)&br[gc];
                float4 hv = *(const float4*)&h[(size_t)gr * 256 + gc];
                ushort4 o;
                o.x = f2bf(sigmoidf_(v[0] + bb.x) * hv.x);
                o.y = f2bf(sigmoidf_(v[1] + bb.y) * hv.y);
                o.z = f2bf(sigmoidf_(v[2] + bb.z) * hv.z);
                o.w = f2bf(sigmoidf_(v[3] + bb.w) * hv.w);
                *(ushort4*)&RH[(size_t)gr * 256 + gc] = o;
            } else if (region == 1) {
                int c = gc - 256;
                float4 bb = *(const float4*)&bz[c];
                ushort4 o;
                o.x = f2bf(sigmoidf_(v[0] + bb.x));
                o.y = f2bf(sigmoidf_(v[1] + bb.y));
                o.z = f2bf(sigmoidf_(v[2] + bb.z));
                o.w = f2bf(sigmoidf_(v[3] + bb.w));
                *(ushort4*)&Zb[(size_t)gr * 256 + c] = o;
            } else {
                int c = gc - 512;
                ushort4 o;
                o.x = f2bf(v[0]); o.y = f2bf(v[1]); o.z = f2bf(v[2]); o.w = f2bf(v[3]);
                *(ushort4*)&Ub[(size_t)gr * 256 + c] = o;
            }
        }
}

// ---------------- HH GEMM with fused h-update epilogue ----------------
__global__ __launch_bounds__(256) void gemm_hh(const unsigned short* __restrict__ A,
                                               const unsigned short* __restrict__ Bt,
                                               const unsigned short* __restrict__ Zb,
                                               const unsigned short* __restrict__ Ub,
                                               const float* __restrict__ bh,
                                               float* __restrict__ h,
                                               unsigned short* __restrict__ hbf,
                                               unsigned short* __restrict__ Xbf) {
    __shared__ __align__(16) unsigned short As[128 * 64];
    __shared__ __align__(16) unsigned short Bs[128 * 64];
    const int bid = blockIdx.x;
    const int wg = (bid & 7) * 32 + (bid >> 3);   // nwg=256, XCD-chunked
    const int bx = wg & 1, by = wg >> 1;
    const int r0 = by << 7, c0 = bx << 7;
    GEMM_CORE64(A, Bt, 256)
#pragma unroll
    for (int m = 0; m < 4; ++m)
#pragma unroll
        for (int n = 0; n < 4; ++n) {
            int gr = erow + m * 16;
            int gc = ecol + n * 16;
            size_t base = (size_t)gr * 256 + gc;
            f32x4 v = acc[m][n];
            float4 bb = *(const float4*)&bh[gc];
            float4 hv = *(const float4*)&h[base];
            ushort4 zp = *(const ushort4*)&Zb[base];
            ushort4 up = *(const ushort4*)&Ub[base];
            float4 hn;
            {
                float z = bf2f(zp.x); hn.x = (1.f - z) * hv.x + z * tanhf(bf2f(up.x) + v[0] + bb.x);
            }{
                float z = bf2f(zp.y); hn.y = (1.f - z) * hv.y + z * tanhf(bf2f(up.y) + v[1] + bb.y);
            }{
                float z = bf2f(zp.z); hn.z = (1.f - z) * hv.z + z * tanhf(bf2f(up.z) + v[2] + bb.z);
            }{
                float z = bf2f(zp.w); hn.w = (1.f - z) * hv.w + z * tanhf(bf2f(up.w) + v[3] + bb.w);
            }
            *(float4*)&h[base] = hn;
            ushort4 o;
            o.x = f2bf(hn.x); o.y = f2bf(hn.y); o.z = f2bf(hn.z); o.w = f2bf(hn.w);
            *(ushort4*)&hbf[base] = o;
            *(ushort4*)&Xbf[(size_t)gr * 768 + 512 + gc] = o;
        }
}

// ---------------- CSR gather: sum message rows per (b,dir,node), bf16 out ----------------
__global__ void gather2_kernel(const unsigned short* __restrict__ msgs,
                               const int* __restrict__ offs, const int* __restrict__ entries,
                               const float* __restrict__ bias, unsigned short* __restrict__ Xb) {
    int wv = threadIdx.x >> 6, lane = threadIdx.x & 63;
    int slot = blockIdx.x * 4 + wv;             // [0, B*2*N)
    int b = slot >> 13;
    int dir = (slot >> 12) & 1;
    int node = slot & 4095;
    const int* o = offs + (size_t)(b * 2 + dir) * OSTRIDE;
    int beg = o[node], end = o[node + 1];
    const int* ent = entries + (size_t)(b * 2 + dir) * EE;
    const float4* bias4 = (const float4*)bias;
    float4 acc = {0.f, 0.f, 0.f, 0.f};
    for (int p = beg; p < end; ++p) {
        int e2 = ent[p];
        int row = e2 >> 4, t = e2 & 15;
        ushort4 pv = *(const ushort4*)(msgs + (size_t)row * DD + lane * 4);
        float4 bv = bias4[t * 64 + lane];
        acc.x += bf2f(pv.x) + bv.x;
        acc.y += bf2f(pv.y) + bv.y;
        acc.z += bf2f(pv.z) + bv.z;
        acc.w += bf2f(pv.w) + bv.w;
    }
    ushort4 o4;
    o4.x = f2bf(acc.x); o4.y = f2bf(acc.y); o4.z = f2bf(acc.z); o4.w = f2bf(acc.w);
    int colbase = (dir == 0 ? 256 : 0) + lane * 4;
    *(ushort4*)(Xb + ((size_t)b * NN + node) * 768 + colbase) = o4;
}

// ---------------- final attention readout ----------------
__global__ void final_reduce(const float* __restrict__ h, const float* __restrict__ ann,
                             const float* __restrict__ Wa, const float* __restrict__ ba,
                             const float* __restrict__ Wo, const float* __restrict__ bo,
                             float* __restrict__ acc) {
    int wv = threadIdx.x >> 6, lane = threadIdx.x & 63;
    int b = blockIdx.x >> 5;
    int nbase = (blockIdx.x & 31) * 128 + wv * 32;
    float4 wah = ((const float4*)Wa)[lane];
    float4 woh = ((const float4*)Wo)[lane];
    float4 waa = {0, 0, 0, 0}, woa = {0, 0, 0, 0};
    if (lane < 16) {
        waa = ((const float4*)(Wa + 256))[lane];
        woa = ((const float4*)(Wo + 256))[lane];
    }
    float bav = ba[0], bov = bo[0];
    float part = 0.f;
    for (int it = 0; it < 32; ++it) {
        int node = nbase + it;
        float4 hv = ((const float4*)(h + ((size_t)b * NN + node) * DD))[lane];
        float sa = hv.x * wah.x + hv.y * wah.y + hv.z * wah.z + hv.w * wah.w;
        float so = hv.x * woh.x + hv.y * woh.y + hv.z * woh.z + hv.w * woh.w;
        if (lane < 16) {
            float4 av = ((const float4*)(ann + ((size_t)b * NN + node) * ADIM))[lane];
            sa += av.x * waa.x + av.y * waa.y + av.z * waa.z + av.w * waa.w;
            so += av.x * woa.x + av.y * woa.y + av.z * woa.z + av.w * woa.w;
        }
        for (int off = 32; off; off >>= 1) {
            sa += __shfl_down(sa, off);
            so += __shfl_down(so, off);
        }
        if (lane == 0) part += sigmoidf_(sa + bav) * tanhf(so + bov);
    }
    if (lane == 0) atomicAdd(&acc[b], part);
}

__global__ void final_out(const float* __restrict__ acc, float* __restrict__ out) {
    int b = threadIdx.x;
    if (b < BB) out[b] = sigmoidf_(acc[b]);
}

extern "C" void kernel_launch(void* const* d_in, const int* in_sizes, int n_in,
                              void* d_out, int out_size, void* d_ws, size_t ws_size,
                              hipStream_t stream) {
    const int*   ann_id     = (const int*)d_in[0];
    const int*   src        = (const int*)d_in[1];
    const int*   dst        = (const int*)d_in[2];
    const int*   etype      = (const int*)d_in[3];
    const float* edge_embed = (const float*)d_in[4];
    const float* edge_bias  = (const float*)d_in[5];
    const float* type_embed = (const float*)d_in[6];
    const float* Wr = (const float*)d_in[7];
    const float* br = (const float*)d_in[8];
    const float* Wz = (const float*)d_in[9];
    const float* bz = (const float*)d_in[10];
    const float* Wh = (const float*)d_in[11];
    const float* bh = (const float*)d_in[12];
    const float* Wa = (const float*)d_in[13];
    const float* ba = (const float*)d_in[14];
    const float* Wo = (const float*)d_in[15];
    const float* bo = (const float*)d_in[16];
    float* out = (float*)d_out;

    char* base = (char*)d_ws;
    size_t off = 0;
    auto alloc = [&](size_t bytes) { char* p = base + off; off += (bytes + 255) & ~(size_t)255; return p; };
    float* ann  = (float*)alloc((size_t)BB * NN * ADIM * 4);          // 4 MB
    float* h    = (float*)alloc((size_t)BB * NN * DD * 4);            // 16 MB
    float* acc  = (float*)alloc(64);
    unsigned short* h_bf   = (unsigned short*)alloc((size_t)BB * NN * DD * 2);   // 8 MB
    unsigned short* W2bf   = (unsigned short*)alloc((size_t)TT * DD * DD * 2);   // 2 MB
    unsigned short* Wcatbf = (unsigned short*)alloc(768 * 768 * 2);
    unsigned short* Whhbf  = (unsigned short*)alloc(256 * 256 * 2);
    unsigned short* msgs   = (unsigned short*)alloc((size_t)MAXM * DD * 2);      // 71 MB
    unsigned short* Xbf    = (unsigned short*)alloc((size_t)BB * NN * 768 * 2);  // 24 MB
    unsigned short* RHbf   = (unsigned short*)alloc((size_t)BB * NN * DD * 2);   // 8 MB
    unsigned short* Zb     = (unsigned short*)alloc((size_t)BB * NN * DD * 2);   // 8 MB
    unsigned short* Ub     = (unsigned short*)alloc((size_t)BB * NN * DD * 2);   // 8 MB
    int* counts  = (int*)alloc((size_t)BB * 2 * NN * 4);              // 128 KB
    int* cursor  = (int*)alloc((size_t)BB * 2 * NN * 4);
    int* offsets = (int*)alloc((size_t)BB * 2 * OSTRIDE * 4);
    int* entries = (int*)alloc((size_t)BB * 2 * EE * 4);              // 512 KB
    int* c32     = (int*)alloc(32 * 4);
    int* tcur    = (int*)alloc(64 * 4);
    int* ttype   = (int*)alloc(MAXTILES * 4);
    int* idx2    = (int*)alloc((size_t)MAXM * 4);                     // 557 KB
    // total ~151 MB

    // ---- prep (once per call) ----
    init_kernel<<<dim3((BB * NN * 64) / 256), dim3(256), 0, stream>>>(
        ann_id, type_embed, ann, h, h_bf, Xbf);
    conv_f2b4<<<dim3((TT * DD * DD) / 1024), dim3(256), 0, stream>>>(edge_embed, W2bf);
    build_wcat<<<dim3((768 * 768) / 256), dim3(256), 0, stream>>>(Wr, Wz, Wh, Wcatbf);
    build_whh<<<dim3((256 * 256) / 256), dim3(256), 0, stream>>>(Wh, Whhbf);
    hipMemsetAsync(counts, 0, (size_t)BB * 2 * NN * 4, stream);
    hipMemsetAsync(c32, 0, 32 * 4, stream);
    hipMemsetAsync(ttype, 0xFF, MAXTILES * 4, stream);
    hipMemsetAsync(idx2, 0, (size_t)MAXM * 4, stream);
    count_kernel<<<dim3((BB * EE) / 256), dim3(256), 0, stream>>>(src, dst, counts);
    count2_kernel<<<dim3((BB * EE) / 256), dim3(256), 0, stream>>>(etype, c32);
    scan_kernel<<<dim3(BB * 2), dim3(1024), 0, stream>>>(counts, offsets, cursor);
    scan2_kernel<<<dim3(1), dim3(64), 0, stream>>>(c32, tcur, ttype);
    fill2_kernel<<<dim3((BB * EE) / 256), dim3(256), 0, stream>>>(
        src, dst, etype, tcur, cursor, entries, idx2);

    for (int s = 0; s < STEPS; ++s) {
        gemm_msgs<<<dim3(MAXTILES * 2), dim3(256), 0, stream>>>(
            h_bf, W2bf, idx2, ttype, msgs);
        gather2_kernel<<<dim3(BB * 2 * NN / 4), dim3(256), 0, stream>>>(
            msgs, offsets, entries, edge_bias, Xbf);
        gemm_rzu<<<dim3(768), dim3(256), 0, stream>>>(
            Xbf, Wcatbf, br, bz, h, RHbf, Zb, Ub);
        gemm_hh<<<dim3(256), dim3(256), 0, stream>>>(
            RHbf, Whhbf, Zb, Ub, bh, h, h_bf, Xbf);
    }

    hipMemsetAsync(acc, 0, 64, stream);
    final_reduce<<<dim3(128), dim3(256), 0, stream>>>(h, ann, Wa, ba, Wo, bo, acc);
    final_out<<<dim3(1), dim3(64), 0, stream>>>(acc, out);
}